// Round 1
// baseline (1026.851 us; speedup 1.0000x reference)
//
#include <hip/hip_runtime.h>
#include <cstdint>

#define D 128
#define GG 64
#define SLICES 16

// ======================= CSR build =======================
__global__ void count_edges_k(const int* __restrict__ dst, int* __restrict__ cnt, int E) {
  int e = blockIdx.x * blockDim.x + threadIdx.x;
  if (e < E) atomicAdd(&cnt[dst[e]], 1);
}

__global__ void graph_ranges_k(const int* __restrict__ batch, int* __restrict__ gstart,
                               int* __restrict__ gcnt, int n) {
  int i = blockIdx.x * blockDim.x + threadIdx.x;
  if (i >= n) return;
  atomicAdd(&gcnt[batch[i]], 1);
  if (i == 0 || batch[i] != batch[i - 1]) gstart[batch[i]] = i;
}

__global__ __launch_bounds__(1024) void scan_k(const int* __restrict__ cnt, int* __restrict__ rp,
                                               int* __restrict__ cur, int n) {
  __shared__ int sd[1024];
  __shared__ int sbase;
  int t = threadIdx.x;
  if (t == 0) sbase = 0;
  __syncthreads();
  for (int base = 0; base < n; base += 1024) {
    int i = base + t;
    int v = (i < n) ? cnt[i] : 0;
    sd[t] = v;
    __syncthreads();
    for (int off = 1; off < 1024; off <<= 1) {
      int u = (t >= off) ? sd[t - off] : 0;
      __syncthreads();
      sd[t] += u;
      __syncthreads();
    }
    if (i < n) { int r = sbase + sd[t] - v; rp[i] = r; cur[i] = r; }
    __syncthreads();
    if (t == 1023) sbase += sd[1023];
    __syncthreads();
  }
  if (t == 0) rp[n] = sbase;
}

__global__ void fill_csr_k(const int* __restrict__ src, const int* __restrict__ dst,
                           int* __restrict__ cur, int* __restrict__ col, int E) {
  int e = blockIdx.x * blockDim.x + threadIdx.x;
  if (e >= E) return;
  int p = atomicAdd(&cur[dst[e]], 1);
  col[p] = src[e];
}

__global__ void dinv_k(const int* __restrict__ cnt, float* __restrict__ dinv, int n) {
  int i = blockIdx.x * blockDim.x + threadIdx.x;
  if (i < n) dinv[i] = rsqrtf((float)cnt[i] + 1.0f);  // deg = in-degree + self-loop
}

// ======================= GEMM: C[M,128] = A[M,128] @ B[128,128] (+bias) =======================
__global__ __launch_bounds__(256) void gemm_k(const float* __restrict__ A, const float* __restrict__ B,
                                              const float* __restrict__ bias, float* __restrict__ C, int M) {
  __shared__ float As[64][33];   // +1 pad breaks bank conflicts on column reads
  __shared__ float Bs[32][128];
  int row0 = blockIdx.x * 64;
  int t = threadIdx.x;
  int cg = (t & 15) * 8;
  int rg = (t >> 4) * 4;
  float acc[4][8];
#pragma unroll
  for (int r = 0; r < 4; ++r)
#pragma unroll
    for (int c = 0; c < 8; ++c) acc[r][c] = 0.f;

  for (int k0 = 0; k0 < 128; k0 += 32) {
#pragma unroll
    for (int l = 0; l < 2; ++l) {           // A chunk: 64 x 32
      int li = t + l * 256;
      int r = li >> 3;
      int kq = (li & 7) * 4;
      float4 v = make_float4(0.f, 0.f, 0.f, 0.f);
      if (row0 + r < M) v = *(const float4*)&A[(size_t)(row0 + r) * 128 + k0 + kq];
      As[r][kq] = v.x; As[r][kq + 1] = v.y; As[r][kq + 2] = v.z; As[r][kq + 3] = v.w;
    }
#pragma unroll
    for (int l = 0; l < 4; ++l) {           // B chunk: 32 x 128
      int li = t + l * 256;
      int r = li >> 5;
      int cq = (li & 31) * 4;
      *(float4*)&Bs[r][cq] = *(const float4*)&B[(size_t)(k0 + r) * 128 + cq];
    }
    __syncthreads();
#pragma unroll 8
    for (int kk = 0; kk < 32; ++kk) {
      float a[4], bv[8];
#pragma unroll
      for (int r = 0; r < 4; ++r) a[r] = As[rg + r][kk];
#pragma unroll
      for (int c = 0; c < 8; ++c) bv[c] = Bs[kk][cg + c];
#pragma unroll
      for (int r = 0; r < 4; ++r)
#pragma unroll
        for (int c = 0; c < 8; ++c) acc[r][c] += a[r] * bv[c];
    }
    __syncthreads();
  }
  float bv2[8];
#pragma unroll
  for (int c = 0; c < 8; ++c) bv2[c] = bias ? bias[cg + c] : 0.f;
#pragma unroll
  for (int r = 0; r < 4; ++r) {
    int row = row0 + rg + r;
    if (row < M) {
      float4 o0 = make_float4(acc[r][0] + bv2[0], acc[r][1] + bv2[1], acc[r][2] + bv2[2], acc[r][3] + bv2[3]);
      float4 o1 = make_float4(acc[r][4] + bv2[4], acc[r][5] + bv2[5], acc[r][6] + bv2[6], acc[r][7] + bv2[7]);
      *(float4*)&C[(size_t)row * 128 + cg] = o0;
      *(float4*)&C[(size_t)row * 128 + cg + 4] = o1;
    }
  }
}

// ======================= GCN aggregation (wave per dst) =======================
__global__ __launch_bounds__(256) void gcn_agg_k(const float* __restrict__ xw, const int* __restrict__ rp,
                                                 const int* __restrict__ col, const float* __restrict__ dinv,
                                                 const float* __restrict__ bias, float* __restrict__ out, int n) {
  int wave = (blockIdx.x * 256 + threadIdx.x) >> 6;
  int lane = threadIdx.x & 63;
  if (wave >= n) return;
  int i = wave;
  float di = dinv[i];
  const float2* base = (const float2*)xw;
  float2 self = base[(size_t)i * 64 + lane];
  float2 acc = make_float2(self.x * di * di, self.y * di * di);
  int e0 = rp[i], e1 = rp[i + 1];
  for (int e = e0; e < e1; ++e) {
    int s = col[e];
    float w = dinv[s] * di;
    float2 v = base[(size_t)s * 64 + lane];
    acc.x += v.x * w;
    acc.y += v.y * w;
  }
  float2 bb = ((const float2*)bias)[lane];
  ((float2*)out)[(size_t)i * 64 + lane] = make_float2(acc.x + bb.x, acc.y + bb.y);
}

// ======================= GAT attention coefficients =======================
__global__ void attn_coef_k(const float* __restrict__ h, const float* __restrict__ a_s,
                            const float* __restrict__ a_d, float* __restrict__ es,
                            float* __restrict__ ed, int n) {
  int idx = blockIdx.x * blockDim.x + threadIdx.x;
  if (idx >= n * 4) return;
  int node = idx >> 2, hh = idx & 3;
  const float4* hr = (const float4*)(h + (size_t)node * 128 + hh * 32);
  const float4* av = (const float4*)(a_s + hh * 32);
  const float4* dv = (const float4*)(a_d + hh * 32);
  float s = 0.f, d2 = 0.f;
#pragma unroll
  for (int q = 0; q < 8; ++q) {
    float4 hv = hr[q], a4 = av[q], d4 = dv[q];
    s  += hv.x * a4.x + hv.y * a4.y + hv.z * a4.z + hv.w * a4.w;
    d2 += hv.x * d4.x + hv.y * d4.y + hv.z * d4.z + hv.w * d4.w;
  }
  es[idx] = s;
  ed[idx] = d2;
}

// ======================= GAT aggregation (wave per dst, online softmax) =======================
__global__ __launch_bounds__(256) void gat_agg_k(const float* __restrict__ hf, const int* __restrict__ rp,
                                                 const int* __restrict__ col, const float* __restrict__ es,
                                                 const float* __restrict__ ed, const float* __restrict__ bias,
                                                 float* __restrict__ out, int n) {
  int wave = (blockIdx.x * 256 + threadIdx.x) >> 6;
  int lane = threadIdx.x & 63;
  if (wave >= n) return;
  int i = wave, hh = lane >> 4;              // lane's dims 2*lane,2*lane+1 are in head lane>>4
  float edi = ed[i * 4 + hh];
  float e_self = es[i * 4 + hh] + edi;
  e_self = e_self >= 0.f ? e_self : 0.2f * e_self;
  float m = e_self, s = 1.0f;
  const float2* base = (const float2*)hf;
  float2 acc = base[(size_t)i * 64 + lane];  // self edge weight exp(0)=1
  int e0 = rp[i], e1 = rp[i + 1];
  for (int e = e0; e < e1; ++e) {
    int sj = col[e];
    float ev = es[sj * 4 + hh] + edi;
    ev = ev >= 0.f ? ev : 0.2f * ev;
    float nm = fmaxf(m, ev);
    float sc = __expf(m - nm);
    float w = __expf(ev - nm);
    float2 v = base[(size_t)sj * 64 + lane];
    acc.x = acc.x * sc + v.x * w;
    acc.y = acc.y * sc + v.y * w;
    s = s * sc + w;
    m = nm;
  }
  float inv = 1.0f / (s + 1e-16f);
  float2 bb = ((const float2*)bias)[lane];
  ((float2*)out)[(size_t)i * 64 + lane] = make_float2(acc.x * inv + bb.x, acc.y * inv + bb.y);
}

// ======================= GraphNorm =======================
__global__ __launch_bounds__(256) void gn_stats_k(const float* __restrict__ h, const int* __restrict__ gstart,
                                                  const int* __restrict__ gcnt, float* __restrict__ gsum,
                                                  float* __restrict__ gsq) {
  int g = blockIdx.x / SLICES, sl = blockIdx.x % SLICES;
  int st = gstart[g], cn = gcnt[g];
  int d = threadIdx.x & 127, half = threadIdx.x >> 7;
  float s = 0.f, ss = 0.f;
  for (int r = sl * 2 + half; r < cn; r += 2 * SLICES) {
    float v = h[(size_t)(st + r) * D + d];
    s += v; ss += v * v;
  }
  __shared__ float l1[128], l2[128];
  if (half) { l1[d] = s; l2[d] = ss; }
  __syncthreads();
  if (!half) {
    atomicAdd(&gsum[g * D + d], s + l1[d]);
    atomicAdd(&gsq[g * D + d], ss + l2[d]);
  }
}

__global__ void gn_finalize_k(const float* __restrict__ gsum, const float* __restrict__ gsq,
                              const int* __restrict__ gcnt, const float* __restrict__ ms,
                              float* __restrict__ mean, float* __restrict__ rstd) {
  int g = blockIdx.x, d = threadIdx.x;
  float cnt = fmaxf((float)gcnt[g], 1.0f);
  float mu = gsum[g * D + d] / cnt;
  float m2 = gsq[g * D + d] / cnt;
  float s = ms[d];
  float var = m2 - (2.0f * s - s * s) * mu * mu;   // E[(x-s*mu)^2]
  mean[g * D + d] = mu;
  rstd[g * D + d] = rsqrtf(fmaxf(var, 0.0f) + 1e-5f);
}

__global__ void gn_apply_k(const float* __restrict__ h, float* __restrict__ x,
                           const int* __restrict__ batch, const float* __restrict__ mean,
                           const float* __restrict__ rstd, const float* __restrict__ w,
                           const float* __restrict__ b, const float* __restrict__ ms, int n) {
  int idx = blockIdx.x * blockDim.x + threadIdx.x;
  if (idx >= n * 32) return;
  int node = idx >> 5, q = idx & 31;
  int g = batch[node];
  int d0 = q * 4;
  float4 hv = ((const float4*)h)[idx];
  float4 xv = ((const float4*)x)[idx];
  float ha[4] = {hv.x, hv.y, hv.z, hv.w};
  float xa[4] = {xv.x, xv.y, xv.z, xv.w};
  float ra[4];
#pragma unroll
  for (int j = 0; j < 4; ++j) {
    int d = d0 + j;
    float sub = ha[j] - ms[d] * mean[g * D + d];
    float v = w[d] * sub * rstd[g * D + d] + b[d];
    ra[j] = fmaxf(v, 0.f) + xa[j];
  }
  ((float4*)x)[idx] = make_float4(ra[0], ra[1], ra[2], ra[3]);
}

// ======================= Hub scores =======================
__global__ __launch_bounds__(256) void hub_k(const float* __restrict__ x, const float* __restrict__ nw1,
                                             const float* __restrict__ nb1, const float* __restrict__ nw2,
                                             const float* __restrict__ nb2, float* __restrict__ out, int n) {
  __shared__ float w1[128 * 64];
  int t = threadIdx.x;
  for (int i = t; i < 128 * 64 / 4; i += 256) ((float4*)w1)[i] = ((const float4*)nw1)[i];
  __syncthreads();
  int lane = t & 63;
  int wv = t >> 6;
  float b1 = nb1[lane];
  float w2 = nw2[lane];
  float b2 = nb2[0];
  for (int node = blockIdx.x * 4 + wv; node < n; node += gridDim.x * 4) {
    const float4* xr = (const float4*)(x + (size_t)node * 128);
    float h = b1;
#pragma unroll 8
    for (int k4 = 0; k4 < 32; ++k4) {
      float4 xv = xr[k4];
      int k = k4 * 4;
      h += xv.x * w1[k * 64 + lane] + xv.y * w1[(k + 1) * 64 + lane] +
           xv.z * w1[(k + 2) * 64 + lane] + xv.w * w1[(k + 3) * 64 + lane];
    }
    h = fmaxf(h, 0.f);
    float c = h * w2;
#pragma unroll
    for (int off = 32; off; off >>= 1) c += __shfl_xor(c, off, 64);
    if (lane == 0) out[node] = 1.0f / (1.0f + __expf(-(c + b2)));
  }
}

// ======================= Pooling =======================
__global__ void init_maxu_k(unsigned* __restrict__ p, int n) {
  int i = blockIdx.x * blockDim.x + threadIdx.x;
  if (i < n) p[i] = 0x007FFFFFu;  // mapped(-inf)
}

__global__ __launch_bounds__(256) void pool_stats_k(const float* __restrict__ x, const int* __restrict__ gstart,
                                                    const int* __restrict__ gcnt, float* __restrict__ gsum,
                                                    unsigned* __restrict__ gmaxu) {
  int g = blockIdx.x / SLICES, sl = blockIdx.x % SLICES;
  int st = gstart[g], cn = gcnt[g];
  int d = threadIdx.x & 127, half = threadIdx.x >> 7;
  float s = 0.f, mx = __uint_as_float(0xFF800000u);  // -inf
  for (int r = sl * 2 + half; r < cn; r += 2 * SLICES) {
    float v = x[(size_t)(st + r) * D + d];
    s += v; mx = fmaxf(mx, v);
  }
  __shared__ float l1[128], l2[128];
  if (half) { l1[d] = s; l2[d] = mx; }
  __syncthreads();
  if (!half) {
    s += l1[d];
    mx = fmaxf(mx, l2[d]);
    atomicAdd(&gsum[g * D + d], s);
    unsigned u = __float_as_uint(mx);
    u = (u & 0x80000000u) ? ~u : (u | 0x80000000u);
    atomicMax(&gmaxu[g * D + d], u);
  }
}

__global__ void pool_fin_k(const float* __restrict__ gsum, const unsigned* __restrict__ gmaxu,
                           const int* __restrict__ gcnt, float* __restrict__ gf) {
  int g = blockIdx.x, d = threadIdx.x;
  float cnt = fmaxf((float)gcnt[g], 1.0f);
  gf[g * 256 + d] = gsum[g * D + d] / cnt;
  unsigned u = gmaxu[g * D + d];
  unsigned bits = (u & 0x80000000u) ? (u ^ 0x80000000u) : ~u;
  gf[g * 256 + 128 + d] = __uint_as_float(bits);
}

// ======================= Graph MLP =======================
__global__ __launch_bounds__(128) void mlp_k(const float* __restrict__ gf, const float* __restrict__ hw1,
                                             const float* __restrict__ hb1, const float* __restrict__ hw2,
                                             const float* __restrict__ hb2, const float* __restrict__ hw3,
                                             const float* __restrict__ hb3, float* __restrict__ logits) {
  __shared__ float sg[256], z1[128], z2[64];
  int g = blockIdx.x, t = threadIdx.x;
  sg[t] = gf[g * 256 + t];
  sg[t + 128] = gf[g * 256 + 128 + t];
  __syncthreads();
  float a = hb1[t];
  for (int k = 0; k < 256; ++k) a += sg[k] * hw1[k * 128 + t];
  z1[t] = fmaxf(a, 0.f);
  __syncthreads();
  if (t < 64) {
    float a2 = hb2[t];
    for (int k = 0; k < 128; ++k) a2 += z1[k] * hw2[k * 64 + t];
    z2[t] = fmaxf(a2, 0.f);
  }
  __syncthreads();
  if (t < 2) {
    float a3 = hb3[t];
    for (int k = 0; k < 64; ++k) a3 += z2[k] * hw3[k * 2 + t];
    logits[g * 2 + t] = a3;
  }
}

// ======================= Host =======================
extern "C" void kernel_launch(void* const* d_in, const int* in_sizes, int n_in,
                              void* d_out, int out_size, void* d_ws, size_t ws_size,
                              hipStream_t stream) {
  const float* x_in  = (const float*)d_in[0];
  const int*   eidx  = (const int*)d_in[1];
  const int*   batch = (const int*)d_in[2];
  const float* Wp  = (const float*)d_in[3];
  const float* bp  = (const float*)d_in[4];
  const float* Wg  = (const float*)d_in[5];
  const float* bg  = (const float*)d_in[6];
  const float* Wa1 = (const float*)d_in[7];
  const float* as1 = (const float*)d_in[8];
  const float* ad1 = (const float*)d_in[9];
  const float* ba1 = (const float*)d_in[10];
  const float* Wa2 = (const float*)d_in[11];
  const float* as2 = (const float*)d_in[12];
  const float* ad2 = (const float*)d_in[13];
  const float* ba2 = (const float*)d_in[14];
  const float* gnw[3] = {(const float*)d_in[15], (const float*)d_in[18], (const float*)d_in[21]};
  const float* gnb[3] = {(const float*)d_in[16], (const float*)d_in[19], (const float*)d_in[22]};
  const float* gns[3] = {(const float*)d_in[17], (const float*)d_in[20], (const float*)d_in[23]};
  const float* hw1 = (const float*)d_in[24];
  const float* hb1 = (const float*)d_in[25];
  const float* hw2 = (const float*)d_in[26];
  const float* hb2 = (const float*)d_in[27];
  const float* hw3 = (const float*)d_in[28];
  const float* hb3 = (const float*)d_in[29];
  const float* nw1 = (const float*)d_in[30];
  const float* nb1 = (const float*)d_in[31];
  const float* nw2 = (const float*)d_in[32];
  const float* nb2 = (const float*)d_in[33];

  const int N = in_sizes[0] / D;
  const int E = in_sizes[1] / 2;
  const int* src = eidx;
  const int* dst = eidx + E;

  float* out    = (float*)d_out;
  float* logits = out;                       // G*2
  float* hub    = out + GG * 2;              // N
  float* gf     = out + GG * 2 + N;          // G*256
  float* X      = out + GG * 2 + N + GG * 256;  // N*128  (x lives in d_out)

  char* wp = (char*)d_ws;
  auto alloc = [&](size_t bytes) { char* p = wp; wp += (bytes + 255) & ~(size_t)255; return p; };
  float* B1      = (float*)alloc((size_t)N * D * 4);
  float* B2      = (float*)alloc((size_t)N * D * 4);
  int*   col     = (int*)alloc((size_t)E * 4);
  int*   cnt     = (int*)alloc((size_t)N * 4);
  int*   rowp    = (int*)alloc((size_t)(N + 1) * 4);
  int*   cur     = (int*)alloc((size_t)N * 4);
  float* dinv    = (float*)alloc((size_t)N * 4);
  float* es      = (float*)alloc((size_t)N * 4 * 4);
  float* ed      = (float*)alloc((size_t)N * 4 * 4);
  float* gsum    = (float*)alloc((size_t)GG * D * 4);
  float* gsq     = (float*)alloc((size_t)GG * D * 4);   // contiguous with gsum
  unsigned* gmaxu = (unsigned*)alloc((size_t)GG * D * 4);
  float* mean    = (float*)alloc((size_t)GG * D * 4);
  float* rstd    = (float*)alloc((size_t)GG * D * 4);
  int*   gcnt    = (int*)alloc((size_t)GG * 4);
  int*   gstart  = (int*)alloc((size_t)GG * 4);
  if ((size_t)(wp - (char*)d_ws) > ws_size) return;  // ws too small -> fail visibly

  // ---- CSR + graph ranges (once; reused by all 3 layers) ----
  hipMemsetAsync(cnt, 0, (size_t)N * 4, stream);
  hipMemsetAsync(gcnt, 0, (size_t)GG * 4, stream);
  hipMemsetAsync(gstart, 0, (size_t)GG * 4, stream);
  count_edges_k<<<(E + 255) / 256, 256, 0, stream>>>(dst, cnt, E);
  graph_ranges_k<<<(N + 255) / 256, 256, 0, stream>>>(batch, gstart, gcnt, N);
  scan_k<<<1, 1024, 0, stream>>>(cnt, rowp, cur, N);
  dinv_k<<<(N + 255) / 256, 256, 0, stream>>>(cnt, dinv, N);
  fill_csr_k<<<(E + 255) / 256, 256, 0, stream>>>(src, dst, cur, col, E);

  const int gemmGrid = (N + 63) / 64;
  const int aggGrid  = (N * 64 + 255) / 256;

  auto graphnorm = [&](int layer) {
    hipMemsetAsync(gsum, 0, 2 * (size_t)GG * D * 4, stream);  // gsum + gsq contiguous
    gn_stats_k<<<GG * SLICES, 256, 0, stream>>>(B2, gstart, gcnt, gsum, gsq);
    gn_finalize_k<<<GG, D, 0, stream>>>(gsum, gsq, gcnt, gns[layer], mean, rstd);
    gn_apply_k<<<(N * 32 + 255) / 256, 256, 0, stream>>>(B2, X, batch, mean, rstd,
                                                         gnw[layer], gnb[layer], gns[layer], N);
  };

  // ---- projection ----
  gemm_k<<<gemmGrid, 256, 0, stream>>>(x_in, Wp, bp, X, N);

  // ---- GCN layer ----
  gemm_k<<<gemmGrid, 256, 0, stream>>>(X, Wg, nullptr, B1, N);
  gcn_agg_k<<<aggGrid, 256, 0, stream>>>(B1, rowp, col, dinv, bg, B2, N);
  graphnorm(0);

  // ---- GAT layer 1 ----
  gemm_k<<<gemmGrid, 256, 0, stream>>>(X, Wa1, nullptr, B1, N);
  attn_coef_k<<<(N * 4 + 255) / 256, 256, 0, stream>>>(B1, as1, ad1, es, ed, N);
  gat_agg_k<<<aggGrid, 256, 0, stream>>>(B1, rowp, col, es, ed, ba1, B2, N);
  graphnorm(1);

  // ---- GAT layer 2 ----
  gemm_k<<<gemmGrid, 256, 0, stream>>>(X, Wa2, nullptr, B1, N);
  attn_coef_k<<<(N * 4 + 255) / 256, 256, 0, stream>>>(B1, as2, ad2, es, ed, N);
  gat_agg_k<<<aggGrid, 256, 0, stream>>>(B1, rowp, col, es, ed, ba2, B2, N);
  graphnorm(2);

  // ---- hub scores ----
  hub_k<<<1024, 256, 0, stream>>>(X, nw1, nb1, nw2, nb2, hub, N);

  // ---- pooling + graph MLP ----
  hipMemsetAsync(gsum, 0, (size_t)GG * D * 4, stream);
  init_maxu_k<<<(GG * D + 255) / 256, 256, 0, stream>>>(gmaxu, GG * D);
  pool_stats_k<<<GG * SLICES, 256, 0, stream>>>(X, gstart, gcnt, gsum, gmaxu);
  pool_fin_k<<<GG, D, 0, stream>>>(gsum, gmaxu, gcnt, gf);
  mlp_k<<<GG, 128, 0, stream>>>(gf, hw1, hb1, hw2, hb2, hw3, hb3, logits);
}

// Round 2
// 789.222 us; speedup vs baseline: 1.3011x; 1.3011x over previous
//
#include <hip/hip_runtime.h>
#include <cstdint>

#define D 128
#define GG 64
#define SLICES 16

// ======================= CSR build =======================
__global__ void count_edges_k(const int* __restrict__ dst, int* __restrict__ cnt, int E) {
  int e = blockIdx.x * blockDim.x + threadIdx.x;
  if (e < E) atomicAdd(&cnt[dst[e]], 1);
}

// batch is sorted: boundary detection, no atomics.
__global__ void bounds_init_k(int* __restrict__ gstart, int* __restrict__ gend) {
  int g = threadIdx.x;
  gstart[g] = 0;
  gend[g] = 0;
}

__global__ void graph_bounds_k(const int* __restrict__ batch, int* __restrict__ gstart,
                               int* __restrict__ gend, int n) {
  int i = blockIdx.x * blockDim.x + threadIdx.x;
  if (i >= n) return;
  int b = batch[i];
  if (i == 0) {
    gstart[b] = 0;
  } else {
    int pb = batch[i - 1];
    if (pb != b) { gstart[b] = i; gend[pb] = i; }
  }
  if (i == n - 1) gend[b] = n;
}

__global__ void gcnt_k(const int* __restrict__ gstart, const int* __restrict__ gend,
                       int* __restrict__ gcnt) {
  int g = threadIdx.x;
  gcnt[g] = gend[g] - gstart[g];
}

__global__ __launch_bounds__(1024) void scan_k(const int* __restrict__ cnt, int* __restrict__ rp,
                                               int* __restrict__ cur, int n) {
  __shared__ int sd[1024];
  __shared__ int sbase;
  int t = threadIdx.x;
  if (t == 0) sbase = 0;
  __syncthreads();
  for (int base = 0; base < n; base += 1024) {
    int i = base + t;
    int v = (i < n) ? cnt[i] : 0;
    sd[t] = v;
    __syncthreads();
    for (int off = 1; off < 1024; off <<= 1) {
      int u = (t >= off) ? sd[t - off] : 0;
      __syncthreads();
      sd[t] += u;
      __syncthreads();
    }
    if (i < n) { int r = sbase + sd[t] - v; rp[i] = r; cur[i] = r; }
    __syncthreads();
    if (t == 1023) sbase += sd[1023];
    __syncthreads();
  }
  if (t == 0) rp[n] = sbase;
}

__global__ void fill_csr_k(const int* __restrict__ src, const int* __restrict__ dst,
                           int* __restrict__ cur, int* __restrict__ col, int E) {
  int e = blockIdx.x * blockDim.x + threadIdx.x;
  if (e >= E) return;
  int p = atomicAdd(&cur[dst[e]], 1);
  col[p] = src[e];
}

__global__ void dinv_k(const int* __restrict__ cnt, float* __restrict__ dinv, int n) {
  int i = blockIdx.x * blockDim.x + threadIdx.x;
  if (i < n) dinv[i] = rsqrtf((float)cnt[i] + 1.0f);  // deg = in-degree + self-loop
}

// ======================= GEMM: C[M,128] = A[M,128] @ B[128,128] (+bias) =======================
__global__ __launch_bounds__(256) void gemm_k(const float* __restrict__ A, const float* __restrict__ B,
                                              const float* __restrict__ bias, float* __restrict__ C, int M) {
  __shared__ float As[64][33];   // +1 pad breaks bank conflicts on column reads
  __shared__ float Bs[32][128];
  int row0 = blockIdx.x * 64;
  int t = threadIdx.x;
  int cg = (t & 15) * 8;
  int rg = (t >> 4) * 4;
  float acc[4][8];
#pragma unroll
  for (int r = 0; r < 4; ++r)
#pragma unroll
    for (int c = 0; c < 8; ++c) acc[r][c] = 0.f;

  for (int k0 = 0; k0 < 128; k0 += 32) {
#pragma unroll
    for (int l = 0; l < 2; ++l) {           // A chunk: 64 x 32
      int li = t + l * 256;
      int r = li >> 3;
      int kq = (li & 7) * 4;
      float4 v = make_float4(0.f, 0.f, 0.f, 0.f);
      if (row0 + r < M) v = *(const float4*)&A[(size_t)(row0 + r) * 128 + k0 + kq];
      As[r][kq] = v.x; As[r][kq + 1] = v.y; As[r][kq + 2] = v.z; As[r][kq + 3] = v.w;
    }
#pragma unroll
    for (int l = 0; l < 4; ++l) {           // B chunk: 32 x 128
      int li = t + l * 256;
      int r = li >> 5;
      int cq = (li & 31) * 4;
      *(float4*)&Bs[r][cq] = *(const float4*)&B[(size_t)(k0 + r) * 128 + cq];
    }
    __syncthreads();
#pragma unroll 8
    for (int kk = 0; kk < 32; ++kk) {
      float a[4], bv[8];
#pragma unroll
      for (int r = 0; r < 4; ++r) a[r] = As[rg + r][kk];
#pragma unroll
      for (int c = 0; c < 8; ++c) bv[c] = Bs[kk][cg + c];
#pragma unroll
      for (int r = 0; r < 4; ++r)
#pragma unroll
        for (int c = 0; c < 8; ++c) acc[r][c] += a[r] * bv[c];
    }
    __syncthreads();
  }
  float bv2[8];
#pragma unroll
  for (int c = 0; c < 8; ++c) bv2[c] = bias ? bias[cg + c] : 0.f;
#pragma unroll
  for (int r = 0; r < 4; ++r) {
    int row = row0 + rg + r;
    if (row < M) {
      float4 o0 = make_float4(acc[r][0] + bv2[0], acc[r][1] + bv2[1], acc[r][2] + bv2[2], acc[r][3] + bv2[3]);
      float4 o1 = make_float4(acc[r][4] + bv2[4], acc[r][5] + bv2[5], acc[r][6] + bv2[6], acc[r][7] + bv2[7]);
      *(float4*)&C[(size_t)row * 128 + cg] = o0;
      *(float4*)&C[(size_t)row * 128 + cg + 4] = o1;
    }
  }
}

// ======================= GCN aggregation (wave per dst) =======================
__global__ __launch_bounds__(256) void gcn_agg_k(const float* __restrict__ xw, const int* __restrict__ rp,
                                                 const int* __restrict__ col, const float* __restrict__ dinv,
                                                 const float* __restrict__ bias, float* __restrict__ out, int n) {
  int wave = (blockIdx.x * 256 + threadIdx.x) >> 6;
  int lane = threadIdx.x & 63;
  if (wave >= n) return;
  int i = wave;
  float di = dinv[i];
  const float2* base = (const float2*)xw;
  float2 self = base[(size_t)i * 64 + lane];
  float2 acc = make_float2(self.x * di * di, self.y * di * di);
  int e0 = rp[i], e1 = rp[i + 1];
  for (int e = e0; e < e1; ++e) {
    int s = col[e];
    float w = dinv[s] * di;
    float2 v = base[(size_t)s * 64 + lane];
    acc.x += v.x * w;
    acc.y += v.y * w;
  }
  float2 bb = ((const float2*)bias)[lane];
  ((float2*)out)[(size_t)i * 64 + lane] = make_float2(acc.x + bb.x, acc.y + bb.y);
}

// ======================= GAT attention coefficients =======================
__global__ void attn_coef_k(const float* __restrict__ h, const float* __restrict__ a_s,
                            const float* __restrict__ a_d, float* __restrict__ es,
                            float* __restrict__ ed, int n) {
  int idx = blockIdx.x * blockDim.x + threadIdx.x;
  if (idx >= n * 4) return;
  int node = idx >> 2, hh = idx & 3;
  const float4* hr = (const float4*)(h + (size_t)node * 128 + hh * 32);
  const float4* av = (const float4*)(a_s + hh * 32);
  const float4* dv = (const float4*)(a_d + hh * 32);
  float s = 0.f, d2 = 0.f;
#pragma unroll
  for (int q = 0; q < 8; ++q) {
    float4 hv = hr[q], a4 = av[q], d4 = dv[q];
    s  += hv.x * a4.x + hv.y * a4.y + hv.z * a4.z + hv.w * a4.w;
    d2 += hv.x * d4.x + hv.y * d4.y + hv.z * d4.z + hv.w * d4.w;
  }
  es[idx] = s;
  ed[idx] = d2;
}

// ======================= GAT aggregation (wave per dst, online softmax) =======================
__global__ __launch_bounds__(256) void gat_agg_k(const float* __restrict__ hf, const int* __restrict__ rp,
                                                 const int* __restrict__ col, const float* __restrict__ es,
                                                 const float* __restrict__ ed, const float* __restrict__ bias,
                                                 float* __restrict__ out, int n) {
  int wave = (blockIdx.x * 256 + threadIdx.x) >> 6;
  int lane = threadIdx.x & 63;
  if (wave >= n) return;
  int i = wave, hh = lane >> 4;              // lane's dims 2*lane,2*lane+1 are in head lane>>4
  float edi = ed[i * 4 + hh];
  float e_self = es[i * 4 + hh] + edi;
  e_self = e_self >= 0.f ? e_self : 0.2f * e_self;
  float m = e_self, s = 1.0f;
  const float2* base = (const float2*)hf;
  float2 acc = base[(size_t)i * 64 + lane];  // self edge weight exp(0)=1
  int e0 = rp[i], e1 = rp[i + 1];
  for (int e = e0; e < e1; ++e) {
    int sj = col[e];
    float ev = es[sj * 4 + hh] + edi;
    ev = ev >= 0.f ? ev : 0.2f * ev;
    float nm = fmaxf(m, ev);
    float sc = __expf(m - nm);
    float w = __expf(ev - nm);
    float2 v = base[(size_t)sj * 64 + lane];
    acc.x = acc.x * sc + v.x * w;
    acc.y = acc.y * sc + v.y * w;
    s = s * sc + w;
    m = nm;
  }
  float inv = 1.0f / (s + 1e-16f);
  float2 bb = ((const float2*)bias)[lane];
  ((float2*)out)[(size_t)i * 64 + lane] = make_float2(acc.x * inv + bb.x, acc.y * inv + bb.y);
}

// ======================= GraphNorm =======================
__global__ __launch_bounds__(256) void gn_stats_k(const float* __restrict__ h, const int* __restrict__ gstart,
                                                  const int* __restrict__ gcnt, float* __restrict__ gsum,
                                                  float* __restrict__ gsq) {
  int g = blockIdx.x / SLICES, sl = blockIdx.x % SLICES;
  int st = gstart[g], cn = gcnt[g];
  int d = threadIdx.x & 127, half = threadIdx.x >> 7;
  float s = 0.f, ss = 0.f;
  for (int r = sl * 2 + half; r < cn; r += 2 * SLICES) {
    float v = h[(size_t)(st + r) * D + d];
    s += v; ss += v * v;
  }
  __shared__ float l1[128], l2[128];
  if (half) { l1[d] = s; l2[d] = ss; }
  __syncthreads();
  if (!half) {
    atomicAdd(&gsum[g * D + d], s + l1[d]);
    atomicAdd(&gsq[g * D + d], ss + l2[d]);
  }
}

__global__ void gn_finalize_k(const float* __restrict__ gsum, const float* __restrict__ gsq,
                              const int* __restrict__ gcnt, const float* __restrict__ ms,
                              float* __restrict__ mean, float* __restrict__ rstd) {
  int g = blockIdx.x, d = threadIdx.x;
  float cnt = fmaxf((float)gcnt[g], 1.0f);
  float mu = gsum[g * D + d] / cnt;
  float m2 = gsq[g * D + d] / cnt;
  float s = ms[d];
  float var = m2 - (2.0f * s - s * s) * mu * mu;   // E[(x-s*mu)^2]
  mean[g * D + d] = mu;
  rstd[g * D + d] = rsqrtf(fmaxf(var, 0.0f) + 1e-5f);
}

__global__ void gn_apply_k(const float* __restrict__ h, float* __restrict__ x,
                           const int* __restrict__ batch, const float* __restrict__ mean,
                           const float* __restrict__ rstd, const float* __restrict__ w,
                           const float* __restrict__ b, const float* __restrict__ ms, int n) {
  int idx = blockIdx.x * blockDim.x + threadIdx.x;
  if (idx >= n * 32) return;
  int node = idx >> 5, q = idx & 31;
  int g = batch[node];
  int d0 = q * 4;
  float4 hv = ((const float4*)h)[idx];
  float4 xv = ((const float4*)x)[idx];
  float ha[4] = {hv.x, hv.y, hv.z, hv.w};
  float xa[4] = {xv.x, xv.y, xv.z, xv.w};
  float ra[4];
#pragma unroll
  for (int j = 0; j < 4; ++j) {
    int d = d0 + j;
    float sub = ha[j] - ms[d] * mean[g * D + d];
    float v = w[d] * sub * rstd[g * D + d] + b[d];
    ra[j] = fmaxf(v, 0.f) + xa[j];
  }
  ((float4*)x)[idx] = make_float4(ra[0], ra[1], ra[2], ra[3]);
}

// ======================= Hub scores =======================
__global__ __launch_bounds__(256) void hub_k(const float* __restrict__ x, const float* __restrict__ nw1,
                                             const float* __restrict__ nb1, const float* __restrict__ nw2,
                                             const float* __restrict__ nb2, float* __restrict__ out, int n) {
  __shared__ float w1[128 * 64];
  int t = threadIdx.x;
  for (int i = t; i < 128 * 64 / 4; i += 256) ((float4*)w1)[i] = ((const float4*)nw1)[i];
  __syncthreads();
  int lane = t & 63;
  int wv = t >> 6;
  float b1 = nb1[lane];
  float w2 = nw2[lane];
  float b2 = nb2[0];
  for (int node = blockIdx.x * 4 + wv; node < n; node += gridDim.x * 4) {
    const float4* xr = (const float4*)(x + (size_t)node * 128);
    float h = b1;
#pragma unroll 8
    for (int k4 = 0; k4 < 32; ++k4) {
      float4 xv = xr[k4];
      int k = k4 * 4;
      h += xv.x * w1[k * 64 + lane] + xv.y * w1[(k + 1) * 64 + lane] +
           xv.z * w1[(k + 2) * 64 + lane] + xv.w * w1[(k + 3) * 64 + lane];
    }
    h = fmaxf(h, 0.f);
    float c = h * w2;
#pragma unroll
    for (int off = 32; off; off >>= 1) c += __shfl_xor(c, off, 64);
    if (lane == 0) out[node] = 1.0f / (1.0f + __expf(-(c + b2)));
  }
}

// ======================= Pooling =======================
__global__ void init_maxu_k(unsigned* __restrict__ p, int n) {
  int i = blockIdx.x * blockDim.x + threadIdx.x;
  if (i < n) p[i] = 0x007FFFFFu;  // mapped(-inf)
}

__global__ __launch_bounds__(256) void pool_stats_k(const float* __restrict__ x, const int* __restrict__ gstart,
                                                    const int* __restrict__ gcnt, float* __restrict__ gsum,
                                                    unsigned* __restrict__ gmaxu) {
  int g = blockIdx.x / SLICES, sl = blockIdx.x % SLICES;
  int st = gstart[g], cn = gcnt[g];
  int d = threadIdx.x & 127, half = threadIdx.x >> 7;
  float s = 0.f, mx = __uint_as_float(0xFF800000u);  // -inf
  for (int r = sl * 2 + half; r < cn; r += 2 * SLICES) {
    float v = x[(size_t)(st + r) * D + d];
    s += v; mx = fmaxf(mx, v);
  }
  __shared__ float l1[128], l2[128];
  if (half) { l1[d] = s; l2[d] = mx; }
  __syncthreads();
  if (!half) {
    s += l1[d];
    mx = fmaxf(mx, l2[d]);
    atomicAdd(&gsum[g * D + d], s);
    unsigned u = __float_as_uint(mx);
    u = (u & 0x80000000u) ? ~u : (u | 0x80000000u);
    atomicMax(&gmaxu[g * D + d], u);
  }
}

__global__ void pool_fin_k(const float* __restrict__ gsum, const unsigned* __restrict__ gmaxu,
                           const int* __restrict__ gcnt, float* __restrict__ gf) {
  int g = blockIdx.x, d = threadIdx.x;
  float cnt = fmaxf((float)gcnt[g], 1.0f);
  gf[g * 256 + d] = gsum[g * D + d] / cnt;
  unsigned u = gmaxu[g * D + d];
  unsigned bits = (u & 0x80000000u) ? (u ^ 0x80000000u) : ~u;
  gf[g * 256 + 128 + d] = __uint_as_float(bits);
}

// ======================= Graph MLP =======================
__global__ __launch_bounds__(128) void mlp_k(const float* __restrict__ gf, const float* __restrict__ hw1,
                                             const float* __restrict__ hb1, const float* __restrict__ hw2,
                                             const float* __restrict__ hb2, const float* __restrict__ hw3,
                                             const float* __restrict__ hb3, float* __restrict__ logits) {
  __shared__ float sg[256], z1[128], z2[64];
  int g = blockIdx.x, t = threadIdx.x;
  sg[t] = gf[g * 256 + t];
  sg[t + 128] = gf[g * 256 + 128 + t];
  __syncthreads();
  float a = hb1[t];
  for (int k = 0; k < 256; ++k) a += sg[k] * hw1[k * 128 + t];
  z1[t] = fmaxf(a, 0.f);
  __syncthreads();
  if (t < 64) {
    float a2 = hb2[t];
    for (int k = 0; k < 128; ++k) a2 += z1[k] * hw2[k * 64 + t];
    z2[t] = fmaxf(a2, 0.f);
  }
  __syncthreads();
  if (t < 2) {
    float a3 = hb3[t];
    for (int k = 0; k < 64; ++k) a3 += z2[k] * hw3[k * 2 + t];
    logits[g * 2 + t] = a3;
  }
}

// ======================= Host =======================
extern "C" void kernel_launch(void* const* d_in, const int* in_sizes, int n_in,
                              void* d_out, int out_size, void* d_ws, size_t ws_size,
                              hipStream_t stream) {
  const float* x_in  = (const float*)d_in[0];
  const int*   eidx  = (const int*)d_in[1];
  const int*   batch = (const int*)d_in[2];
  const float* Wp  = (const float*)d_in[3];
  const float* bp  = (const float*)d_in[4];
  const float* Wg  = (const float*)d_in[5];
  const float* bg  = (const float*)d_in[6];
  const float* Wa1 = (const float*)d_in[7];
  const float* as1 = (const float*)d_in[8];
  const float* ad1 = (const float*)d_in[9];
  const float* ba1 = (const float*)d_in[10];
  const float* Wa2 = (const float*)d_in[11];
  const float* as2 = (const float*)d_in[12];
  const float* ad2 = (const float*)d_in[13];
  const float* ba2 = (const float*)d_in[14];
  const float* gnw[3] = {(const float*)d_in[15], (const float*)d_in[18], (const float*)d_in[21]};
  const float* gnb[3] = {(const float*)d_in[16], (const float*)d_in[19], (const float*)d_in[22]};
  const float* gns[3] = {(const float*)d_in[17], (const float*)d_in[20], (const float*)d_in[23]};
  const float* hw1 = (const float*)d_in[24];
  const float* hb1 = (const float*)d_in[25];
  const float* hw2 = (const float*)d_in[26];
  const float* hb2 = (const float*)d_in[27];
  const float* hw3 = (const float*)d_in[28];
  const float* hb3 = (const float*)d_in[29];
  const float* nw1 = (const float*)d_in[30];
  const float* nb1 = (const float*)d_in[31];
  const float* nw2 = (const float*)d_in[32];
  const float* nb2 = (const float*)d_in[33];

  const int N = in_sizes[0] / D;
  const int E = in_sizes[1] / 2;
  const int* src = eidx;
  const int* dst = eidx + E;

  float* out    = (float*)d_out;
  float* logits = out;                       // G*2
  float* hub    = out + GG * 2;              // N
  float* gf     = out + GG * 2 + N;          // G*256
  float* X      = out + GG * 2 + N + GG * 256;  // N*128  (x lives in d_out)

  char* wp = (char*)d_ws;
  auto alloc = [&](size_t bytes) { char* p = wp; wp += (bytes + 255) & ~(size_t)255; return p; };
  float* B1      = (float*)alloc((size_t)N * D * 4);
  float* B2      = (float*)alloc((size_t)N * D * 4);
  int*   col     = (int*)alloc((size_t)E * 4);
  int*   cnt     = (int*)alloc((size_t)N * 4);
  int*   rowp    = (int*)alloc((size_t)(N + 1) * 4);
  int*   cur     = (int*)alloc((size_t)N * 4);
  float* dinv    = (float*)alloc((size_t)N * 4);
  float* es      = (float*)alloc((size_t)N * 4 * 4);
  float* ed      = (float*)alloc((size_t)N * 4 * 4);
  float* gsum    = (float*)alloc((size_t)GG * D * 4);
  float* gsq     = (float*)alloc((size_t)GG * D * 4);   // contiguous with gsum
  unsigned* gmaxu = (unsigned*)alloc((size_t)GG * D * 4);
  float* mean    = (float*)alloc((size_t)GG * D * 4);
  float* rstd    = (float*)alloc((size_t)GG * D * 4);
  int*   gcnt    = (int*)alloc((size_t)GG * 4);
  int*   gstart  = (int*)alloc((size_t)GG * 4);
  int*   gend    = (int*)alloc((size_t)GG * 4);
  if ((size_t)(wp - (char*)d_ws) > ws_size) return;  // ws too small -> fail visibly

  // ---- CSR + graph ranges (once; reused by all 3 layers) ----
  hipMemsetAsync(cnt, 0, (size_t)N * 4, stream);
  count_edges_k<<<(E + 255) / 256, 256, 0, stream>>>(dst, cnt, E);
  bounds_init_k<<<1, GG, 0, stream>>>(gstart, gend);
  graph_bounds_k<<<(N + 255) / 256, 256, 0, stream>>>(batch, gstart, gend, N);
  gcnt_k<<<1, GG, 0, stream>>>(gstart, gend, gcnt);
  scan_k<<<1, 1024, 0, stream>>>(cnt, rowp, cur, N);
  dinv_k<<<(N + 255) / 256, 256, 0, stream>>>(cnt, dinv, N);
  fill_csr_k<<<(E + 255) / 256, 256, 0, stream>>>(src, dst, cur, col, E);

  const int gemmGrid = (N + 63) / 64;
  const int aggGrid  = (N * 64 + 255) / 256;

  auto graphnorm = [&](int layer) {
    hipMemsetAsync(gsum, 0, 2 * (size_t)GG * D * 4, stream);  // gsum + gsq contiguous
    gn_stats_k<<<GG * SLICES, 256, 0, stream>>>(B2, gstart, gcnt, gsum, gsq);
    gn_finalize_k<<<GG, D, 0, stream>>>(gsum, gsq, gcnt, gns[layer], mean, rstd);
    gn_apply_k<<<(N * 32 + 255) / 256, 256, 0, stream>>>(B2, X, batch, mean, rstd,
                                                         gnw[layer], gnb[layer], gns[layer], N);
  };

  // ---- projection ----
  gemm_k<<<gemmGrid, 256, 0, stream>>>(x_in, Wp, bp, X, N);

  // ---- GCN layer ----
  gemm_k<<<gemmGrid, 256, 0, stream>>>(X, Wg, nullptr, B1, N);
  gcn_agg_k<<<aggGrid, 256, 0, stream>>>(B1, rowp, col, dinv, bg, B2, N);
  graphnorm(0);

  // ---- GAT layer 1 ----
  gemm_k<<<gemmGrid, 256, 0, stream>>>(X, Wa1, nullptr, B1, N);
  attn_coef_k<<<(N * 4 + 255) / 256, 256, 0, stream>>>(B1, as1, ad1, es, ed, N);
  gat_agg_k<<<aggGrid, 256, 0, stream>>>(B1, rowp, col, es, ed, ba1, B2, N);
  graphnorm(1);

  // ---- GAT layer 2 ----
  gemm_k<<<gemmGrid, 256, 0, stream>>>(X, Wa2, nullptr, B1, N);
  attn_coef_k<<<(N * 4 + 255) / 256, 256, 0, stream>>>(B1, as2, ad2, es, ed, N);
  gat_agg_k<<<aggGrid, 256, 0, stream>>>(B1, rowp, col, es, ed, ba2, B2, N);
  graphnorm(2);

  // ---- hub scores ----
  hub_k<<<1024, 256, 0, stream>>>(X, nw1, nb1, nw2, nb2, hub, N);

  // ---- pooling + graph MLP ----
  hipMemsetAsync(gsum, 0, (size_t)GG * D * 4, stream);
  init_maxu_k<<<(GG * D + 255) / 256, 256, 0, stream>>>(gmaxu, GG * D);
  pool_stats_k<<<GG * SLICES, 256, 0, stream>>>(X, gstart, gcnt, gsum, gmaxu);
  pool_fin_k<<<GG, D, 0, stream>>>(gsum, gmaxu, gcnt, gf);
  mlp_k<<<GG, 128, 0, stream>>>(gf, hw1, hb1, hw2, hb2, hw3, hb3, logits);
}

// Round 3
// 601.181 us; speedup vs baseline: 1.7081x; 1.3128x over previous
//
#include <hip/hip_runtime.h>
#include <cstdint>

#define D 128
#define GG 64
#define SLICES 16

// ---------- bf16 helpers ----------
__device__ inline unsigned packbf2(float a, float b) {
  unsigned ua = __float_as_uint(a), ub = __float_as_uint(b);
  ua = (ua + 0x7FFFu + ((ua >> 16) & 1u)) >> 16;   // RNE
  ub = (ub + 0x7FFFu + ((ub >> 16) & 1u)) >> 16;
  return ua | (ub << 16);
}
__device__ inline float2 unpackbf2(unsigned u) {
  return make_float2(__uint_as_float(u << 16), __uint_as_float(u & 0xFFFF0000u));
}

// ======================= CSR build =======================
__global__ void count_edges_k(const int* __restrict__ dst, int* __restrict__ cnt, int E) {
  int e = blockIdx.x * blockDim.x + threadIdx.x;
  if (e < E) atomicAdd(&cnt[dst[e]], 1);
}

__global__ void bounds_init_k(int* __restrict__ gstart, int* __restrict__ gend) {
  int g = threadIdx.x;
  gstart[g] = 0;
  gend[g] = 0;
}

__global__ void graph_bounds_k(const int* __restrict__ batch, int* __restrict__ gstart,
                               int* __restrict__ gend, int n) {
  int i = blockIdx.x * blockDim.x + threadIdx.x;
  if (i >= n) return;
  int b = batch[i];
  if (i == 0) {
    gstart[b] = 0;
  } else {
    int pb = batch[i - 1];
    if (pb != b) { gstart[b] = i; gend[pb] = i; }
  }
  if (i == n - 1) gend[b] = n;
}

__global__ void gcnt_k(const int* __restrict__ gstart, const int* __restrict__ gend,
                       int* __restrict__ gcnt) {
  int g = threadIdx.x;
  gcnt[g] = gend[g] - gstart[g];
}

// Hierarchical exclusive scan of cnt[0..n) -> rp, cur; rp[n]=E.
__global__ __launch_bounds__(256) void scan1_k(const int* __restrict__ cnt, int* __restrict__ rp,
                                               int* __restrict__ bsum, int n) {
  __shared__ int sd[256];
  int t = threadIdx.x;
  int i = blockIdx.x * 256 + t;
  int v = (i < n) ? cnt[i] : 0;
  sd[t] = v;
  __syncthreads();
#pragma unroll
  for (int off = 1; off < 256; off <<= 1) {
    int u = (t >= off) ? sd[t - off] : 0;
    __syncthreads();
    sd[t] += u;
    __syncthreads();
  }
  if (i < n) rp[i] = sd[t] - v;
  if (t == 255) bsum[blockIdx.x] = sd[255];
}

__global__ __launch_bounds__(256) void scan2_k(int* __restrict__ bsum, int nb) {
  __shared__ int sd[256];
  int t = threadIdx.x;
  int v = (t < nb) ? bsum[t] : 0;
  sd[t] = v;
  __syncthreads();
#pragma unroll
  for (int off = 1; off < 256; off <<= 1) {
    int u = (t >= off) ? sd[t - off] : 0;
    __syncthreads();
    sd[t] += u;
    __syncthreads();
  }
  if (t < nb) bsum[t] = sd[t] - v;
}

__global__ __launch_bounds__(256) void scan3_k(int* __restrict__ rp, const int* __restrict__ bsum,
                                               int* __restrict__ cur, int n, int E) {
  int i = blockIdx.x * 256 + threadIdx.x;
  if (i < n) {
    int r = rp[i] + bsum[blockIdx.x];
    rp[i] = r;
    cur[i] = r;
  }
  if (i == 0) rp[n] = E;
}

__global__ void fill_csr_k(const int* __restrict__ src, const int* __restrict__ dst,
                           int* __restrict__ cur, int* __restrict__ col, int E) {
  int e = blockIdx.x * blockDim.x + threadIdx.x;
  if (e >= E) return;
  int p = atomicAdd(&cur[dst[e]], 1);
  col[p] = src[e];
}

__global__ void dinv_k(const int* __restrict__ cnt, float* __restrict__ dinv, int n) {
  int i = blockIdx.x * blockDim.x + threadIdx.x;
  if (i < n) dinv[i] = rsqrtf((float)cnt[i] + 1.0f);  // deg = in-degree + self-loop
}

// ======================= GEMM: C[M,128] = A[M,128] @ B[128,128] (+bias, optional bf16 copy) ===
__global__ __launch_bounds__(256) void gemm_k(const float* __restrict__ A, const float* __restrict__ B,
                                              const float* __restrict__ bias, float* __restrict__ C,
                                              unsigned* __restrict__ Cb, int M) {
  __shared__ float As[64][33];
  __shared__ float Bs[32][128];
  int row0 = blockIdx.x * 64;
  int t = threadIdx.x;
  int cg = (t & 15) * 8;
  int rg = (t >> 4) * 4;
  float acc[4][8];
#pragma unroll
  for (int r = 0; r < 4; ++r)
#pragma unroll
    for (int c = 0; c < 8; ++c) acc[r][c] = 0.f;

  for (int k0 = 0; k0 < 128; k0 += 32) {
#pragma unroll
    for (int l = 0; l < 2; ++l) {
      int li = t + l * 256;
      int r = li >> 3;
      int kq = (li & 7) * 4;
      float4 v = make_float4(0.f, 0.f, 0.f, 0.f);
      if (row0 + r < M) v = *(const float4*)&A[(size_t)(row0 + r) * 128 + k0 + kq];
      As[r][kq] = v.x; As[r][kq + 1] = v.y; As[r][kq + 2] = v.z; As[r][kq + 3] = v.w;
    }
#pragma unroll
    for (int l = 0; l < 4; ++l) {
      int li = t + l * 256;
      int r = li >> 5;
      int cq = (li & 31) * 4;
      *(float4*)&Bs[r][cq] = *(const float4*)&B[(size_t)(k0 + r) * 128 + cq];
    }
    __syncthreads();
#pragma unroll 8
    for (int kk = 0; kk < 32; ++kk) {
      float a[4], bv[8];
#pragma unroll
      for (int r = 0; r < 4; ++r) a[r] = As[rg + r][kk];
#pragma unroll
      for (int c = 0; c < 8; ++c) bv[c] = Bs[kk][cg + c];
#pragma unroll
      for (int r = 0; r < 4; ++r)
#pragma unroll
        for (int c = 0; c < 8; ++c) acc[r][c] += a[r] * bv[c];
    }
    __syncthreads();
  }
  float bv2[8];
#pragma unroll
  for (int c = 0; c < 8; ++c) bv2[c] = bias ? bias[cg + c] : 0.f;
#pragma unroll
  for (int r = 0; r < 4; ++r) {
    int row = row0 + rg + r;
    if (row < M) {
      float o[8];
#pragma unroll
      for (int c = 0; c < 8; ++c) o[c] = acc[r][c] + bv2[c];
      *(float4*)&C[(size_t)row * 128 + cg] = make_float4(o[0], o[1], o[2], o[3]);
      *(float4*)&C[(size_t)row * 128 + cg + 4] = make_float4(o[4], o[5], o[6], o[7]);
      if (Cb) {
        uint4 p;
        p.x = packbf2(o[0], o[1]); p.y = packbf2(o[2], o[3]);
        p.z = packbf2(o[4], o[5]); p.w = packbf2(o[6], o[7]);
        *(uint4*)&Cb[(size_t)row * 64 + cg / 2] = p;
      }
    }
  }
}

// ======================= GCN aggregation (bf16 gathers) =======================
__global__ __launch_bounds__(256) void gcn_gather_k(const unsigned* __restrict__ xwb,
                                                    const int* __restrict__ rp, const int* __restrict__ col,
                                                    const float* __restrict__ dinv, const float* __restrict__ bias,
                                                    float* __restrict__ out, int n) {
  int i = blockIdx.x * 4 + (threadIdx.x >> 6);
  if (i >= n) return;
  int lane = threadIdx.x & 63;
  int e0 = __builtin_amdgcn_readfirstlane(rp[i]);
  int e1 = __builtin_amdgcn_readfirstlane(rp[i + 1]);
  float di = dinv[i];
  float2 sv = unpackbf2(xwb[(size_t)i * 64 + lane]);
  float ax0 = sv.x * di * di, ay0 = sv.y * di * di, ax1 = 0.f, ay1 = 0.f;
  int e = e0;
  for (; e + 1 < e1; e += 2) {
    int s0 = __builtin_amdgcn_readfirstlane(col[e]);
    int s1 = __builtin_amdgcn_readfirstlane(col[e + 1]);
    float w0 = dinv[s0] * di, w1 = dinv[s1] * di;
    float2 v0 = unpackbf2(xwb[(size_t)s0 * 64 + lane]);
    float2 v1 = unpackbf2(xwb[(size_t)s1 * 64 + lane]);
    ax0 += v0.x * w0; ay0 += v0.y * w0;
    ax1 += v1.x * w1; ay1 += v1.y * w1;
  }
  if (e < e1) {
    int s0 = __builtin_amdgcn_readfirstlane(col[e]);
    float w0 = dinv[s0] * di;
    float2 v0 = unpackbf2(xwb[(size_t)s0 * 64 + lane]);
    ax0 += v0.x * w0; ay0 += v0.y * w0;
  }
  float2 bb = ((const float2*)bias)[lane];
  ((float2*)out)[(size_t)i * 64 + lane] = make_float2(ax0 + ax1 + bb.x, ay0 + ay1 + bb.y);
}

// ======================= GAT attention coefficients =======================
__global__ void attn_coef_k(const float* __restrict__ h, const float* __restrict__ a_s,
                            const float* __restrict__ a_d, float* __restrict__ es,
                            float* __restrict__ ed, int n) {
  int idx = blockIdx.x * blockDim.x + threadIdx.x;
  if (idx >= n * 4) return;
  int node = idx >> 2, hh = idx & 3;
  const float4* hr = (const float4*)(h + (size_t)node * 128 + hh * 32);
  const float4* av = (const float4*)(a_s + hh * 32);
  const float4* dv = (const float4*)(a_d + hh * 32);
  float s = 0.f, d2 = 0.f;
#pragma unroll
  for (int q = 0; q < 8; ++q) {
    float4 hv = hr[q], a4 = av[q], d4 = dv[q];
    s  += hv.x * a4.x + hv.y * a4.y + hv.z * a4.z + hv.w * a4.w;
    d2 += hv.x * d4.x + hv.y * d4.y + hv.z * d4.z + hv.w * d4.w;
  }
  es[idx] = s;
  ed[idx] = d2;
}

// ======================= GAT alpha precompute (exact two-phase softmax) =======================
__global__ __launch_bounds__(256) void alpha_k(const float* __restrict__ es, const float* __restrict__ ed,
                                               const int* __restrict__ rp, const int* __restrict__ col,
                                               float* __restrict__ alpha, float* __restrict__ aself, int n) {
  int i = blockIdx.x * 4 + (threadIdx.x >> 6);
  if (i >= n) return;
  int lane = threadIdx.x & 63;
  int hh = lane >> 4, slot = lane & 15;
  int e0 = __builtin_amdgcn_readfirstlane(rp[i]);
  int e1 = __builtin_amdgcn_readfirstlane(rp[i + 1]);
  float edi = ed[i * 4 + hh];
  float esf = es[i * 4 + hh] + edi;
  esf = esf >= 0.f ? esf : 0.2f * esf;
  float m = esf;
  for (int e = e0 + slot; e < e1; e += 16) {
    int sj = col[e];
    float ev = es[sj * 4 + hh] + edi;
    ev = ev >= 0.f ? ev : 0.2f * ev;
    alpha[(size_t)e * 4 + hh] = ev;
    m = fmaxf(m, ev);
  }
#pragma unroll
  for (int off = 1; off < 16; off <<= 1) m = fmaxf(m, __shfl_xor(m, off, 64));
  float s = (slot == 0) ? __expf(esf - m) : 0.f;
  for (int e = e0 + slot; e < e1; e += 16) {
    float w = __expf(alpha[(size_t)e * 4 + hh] - m);
    alpha[(size_t)e * 4 + hh] = w;
    s += w;
  }
#pragma unroll
  for (int off = 1; off < 16; off <<= 1) s += __shfl_xor(s, off, 64);
  float winv = 1.0f / (s + 1e-16f);
  for (int e = e0 + slot; e < e1; e += 16) {
    alpha[(size_t)e * 4 + hh] *= winv;
  }
  if (slot == 0) aself[i * 4 + hh] = __expf(esf - m) * winv;
}

// ======================= GAT gather (bf16 features, precomputed alpha) =======================
__global__ __launch_bounds__(256) void gat_gather_k(const unsigned* __restrict__ hfb,
                                                    const int* __restrict__ rp, const int* __restrict__ col,
                                                    const float* __restrict__ alpha, const float* __restrict__ aself,
                                                    const float* __restrict__ bias, float* __restrict__ out, int n) {
  int i = blockIdx.x * 4 + (threadIdx.x >> 6);
  if (i >= n) return;
  int lane = threadIdx.x & 63;
  int hh = lane >> 4;
  int e0 = __builtin_amdgcn_readfirstlane(rp[i]);
  int e1 = __builtin_amdgcn_readfirstlane(rp[i + 1]);
  float2 sv = unpackbf2(hfb[(size_t)i * 64 + lane]);
  float a0 = aself[i * 4 + hh];
  float ax0 = sv.x * a0, ay0 = sv.y * a0, ax1 = 0.f, ay1 = 0.f;
  int e = e0;
  for (; e + 1 < e1; e += 2) {
    int s0 = __builtin_amdgcn_readfirstlane(col[e]);
    int s1 = __builtin_amdgcn_readfirstlane(col[e + 1]);
    float aa0 = alpha[(size_t)e * 4 + hh];
    float aa1 = alpha[(size_t)(e + 1) * 4 + hh];
    float2 v0 = unpackbf2(hfb[(size_t)s0 * 64 + lane]);
    float2 v1 = unpackbf2(hfb[(size_t)s1 * 64 + lane]);
    ax0 += v0.x * aa0; ay0 += v0.y * aa0;
    ax1 += v1.x * aa1; ay1 += v1.y * aa1;
  }
  if (e < e1) {
    int s0 = __builtin_amdgcn_readfirstlane(col[e]);
    float aa0 = alpha[(size_t)e * 4 + hh];
    float2 v0 = unpackbf2(hfb[(size_t)s0 * 64 + lane]);
    ax0 += v0.x * aa0; ay0 += v0.y * aa0;
  }
  float2 bb = ((const float2*)bias)[lane];
  ((float2*)out)[(size_t)i * 64 + lane] = make_float2(ax0 + ax1 + bb.x, ay0 + ay1 + bb.y);
}

// ======================= GraphNorm =======================
__global__ __launch_bounds__(256) void gn_stats_k(const float* __restrict__ h, const int* __restrict__ gstart,
                                                  const int* __restrict__ gcnt, float* __restrict__ gsum,
                                                  float* __restrict__ gsq) {
  int g = blockIdx.x / SLICES, sl = blockIdx.x % SLICES;
  int st = gstart[g], cn = gcnt[g];
  int d = threadIdx.x & 127, half = threadIdx.x >> 7;
  float s = 0.f, ss = 0.f;
  for (int r = sl * 2 + half; r < cn; r += 2 * SLICES) {
    float v = h[(size_t)(st + r) * D + d];
    s += v; ss += v * v;
  }
  __shared__ float l1[128], l2[128];
  if (half) { l1[d] = s; l2[d] = ss; }
  __syncthreads();
  if (!half) {
    atomicAdd(&gsum[g * D + d], s + l1[d]);
    atomicAdd(&gsq[g * D + d], ss + l2[d]);
  }
}

__global__ void gn_finalize_k(const float* __restrict__ gsum, const float* __restrict__ gsq,
                              const int* __restrict__ gcnt, const float* __restrict__ ms,
                              float* __restrict__ mean, float* __restrict__ rstd) {
  int g = blockIdx.x, d = threadIdx.x;
  float cnt = fmaxf((float)gcnt[g], 1.0f);
  float mu = gsum[g * D + d] / cnt;
  float m2 = gsq[g * D + d] / cnt;
  float s = ms[d];
  float var = m2 - (2.0f * s - s * s) * mu * mu;
  mean[g * D + d] = mu;
  rstd[g * D + d] = rsqrtf(fmaxf(var, 0.0f) + 1e-5f);
}

__global__ void gn_apply_k(const float* __restrict__ h, float* __restrict__ x,
                           const int* __restrict__ batch, const float* __restrict__ mean,
                           const float* __restrict__ rstd, const float* __restrict__ w,
                           const float* __restrict__ b, const float* __restrict__ ms, int n) {
  int idx = blockIdx.x * blockDim.x + threadIdx.x;
  if (idx >= n * 32) return;
  int node = idx >> 5, q = idx & 31;
  int g = batch[node];
  int d0 = q * 4;
  float4 hv = ((const float4*)h)[idx];
  float4 xv = ((const float4*)x)[idx];
  float ha[4] = {hv.x, hv.y, hv.z, hv.w};
  float xa[4] = {xv.x, xv.y, xv.z, xv.w};
  float ra[4];
#pragma unroll
  for (int j = 0; j < 4; ++j) {
    int d = d0 + j;
    float sub = ha[j] - ms[d] * mean[g * D + d];
    float v = w[d] * sub * rstd[g * D + d] + b[d];
    ra[j] = fmaxf(v, 0.f) + xa[j];
  }
  ((float4*)x)[idx] = make_float4(ra[0], ra[1], ra[2], ra[3]);
}

// ======================= Hub scores =======================
__global__ __launch_bounds__(256) void hub_k(const float* __restrict__ x, const float* __restrict__ nw1,
                                             const float* __restrict__ nb1, const float* __restrict__ nw2,
                                             const float* __restrict__ nb2, float* __restrict__ out, int n) {
  __shared__ float w1[128 * 64];
  int t = threadIdx.x;
  for (int i = t; i < 128 * 64 / 4; i += 256) ((float4*)w1)[i] = ((const float4*)nw1)[i];
  __syncthreads();
  int lane = t & 63;
  int wv = t >> 6;
  float b1 = nb1[lane];
  float w2 = nw2[lane];
  float b2 = nb2[0];
  for (int node = blockIdx.x * 4 + wv; node < n; node += gridDim.x * 4) {
    const float4* xr = (const float4*)(x + (size_t)node * 128);
    float h = b1;
#pragma unroll 8
    for (int k4 = 0; k4 < 32; ++k4) {
      float4 xv = xr[k4];
      int k = k4 * 4;
      h += xv.x * w1[k * 64 + lane] + xv.y * w1[(k + 1) * 64 + lane] +
           xv.z * w1[(k + 2) * 64 + lane] + xv.w * w1[(k + 3) * 64 + lane];
    }
    h = fmaxf(h, 0.f);
    float c = h * w2;
#pragma unroll
    for (int off = 32; off; off >>= 1) c += __shfl_xor(c, off, 64);
    if (lane == 0) out[node] = 1.0f / (1.0f + __expf(-(c + b2)));
  }
}

// ======================= Pooling =======================
__global__ void init_maxu_k(unsigned* __restrict__ p, int n) {
  int i = blockIdx.x * blockDim.x + threadIdx.x;
  if (i < n) p[i] = 0x007FFFFFu;
}

__global__ __launch_bounds__(256) void pool_stats_k(const float* __restrict__ x, const int* __restrict__ gstart,
                                                    const int* __restrict__ gcnt, float* __restrict__ gsum,
                                                    unsigned* __restrict__ gmaxu) {
  int g = blockIdx.x / SLICES, sl = blockIdx.x % SLICES;
  int st = gstart[g], cn = gcnt[g];
  int d = threadIdx.x & 127, half = threadIdx.x >> 7;
  float s = 0.f, mx = __uint_as_float(0xFF800000u);
  for (int r = sl * 2 + half; r < cn; r += 2 * SLICES) {
    float v = x[(size_t)(st + r) * D + d];
    s += v; mx = fmaxf(mx, v);
  }
  __shared__ float l1[128], l2[128];
  if (half) { l1[d] = s; l2[d] = mx; }
  __syncthreads();
  if (!half) {
    s += l1[d];
    mx = fmaxf(mx, l2[d]);
    atomicAdd(&gsum[g * D + d], s);
    unsigned u = __float_as_uint(mx);
    u = (u & 0x80000000u) ? ~u : (u | 0x80000000u);
    atomicMax(&gmaxu[g * D + d], u);
  }
}

__global__ void pool_fin_k(const float* __restrict__ gsum, const unsigned* __restrict__ gmaxu,
                           const int* __restrict__ gcnt, float* __restrict__ gf) {
  int g = blockIdx.x, d = threadIdx.x;
  float cnt = fmaxf((float)gcnt[g], 1.0f);
  gf[g * 256 + d] = gsum[g * D + d] / cnt;
  unsigned u = gmaxu[g * D + d];
  unsigned bits = (u & 0x80000000u) ? (u ^ 0x80000000u) : ~u;
  gf[g * 256 + 128 + d] = __uint_as_float(bits);
}

// ======================= Graph MLP =======================
__global__ __launch_bounds__(128) void mlp_k(const float* __restrict__ gf, const float* __restrict__ hw1,
                                             const float* __restrict__ hb1, const float* __restrict__ hw2,
                                             const float* __restrict__ hb2, const float* __restrict__ hw3,
                                             const float* __restrict__ hb3, float* __restrict__ logits) {
  __shared__ float sg[256], z1[128], z2[64];
  int g = blockIdx.x, t = threadIdx.x;
  sg[t] = gf[g * 256 + t];
  sg[t + 128] = gf[g * 256 + 128 + t];
  __syncthreads();
  float a = hb1[t];
  for (int k = 0; k < 256; ++k) a += sg[k] * hw1[k * 128 + t];
  z1[t] = fmaxf(a, 0.f);
  __syncthreads();
  if (t < 64) {
    float a2 = hb2[t];
    for (int k = 0; k < 128; ++k) a2 += z1[k] * hw2[k * 64 + t];
    z2[t] = fmaxf(a2, 0.f);
  }
  __syncthreads();
  if (t < 2) {
    float a3 = hb3[t];
    for (int k = 0; k < 64; ++k) a3 += z2[k] * hw3[k * 2 + t];
    logits[g * 2 + t] = a3;
  }
}

// ======================= Host =======================
extern "C" void kernel_launch(void* const* d_in, const int* in_sizes, int n_in,
                              void* d_out, int out_size, void* d_ws, size_t ws_size,
                              hipStream_t stream) {
  const float* x_in  = (const float*)d_in[0];
  const int*   eidx  = (const int*)d_in[1];
  const int*   batch = (const int*)d_in[2];
  const float* Wp  = (const float*)d_in[3];
  const float* bp  = (const float*)d_in[4];
  const float* Wg  = (const float*)d_in[5];
  const float* bg  = (const float*)d_in[6];
  const float* Wa1 = (const float*)d_in[7];
  const float* as1 = (const float*)d_in[8];
  const float* ad1 = (const float*)d_in[9];
  const float* ba1 = (const float*)d_in[10];
  const float* Wa2 = (const float*)d_in[11];
  const float* as2 = (const float*)d_in[12];
  const float* ad2 = (const float*)d_in[13];
  const float* ba2 = (const float*)d_in[14];
  const float* gnw[3] = {(const float*)d_in[15], (const float*)d_in[18], (const float*)d_in[21]};
  const float* gnb[3] = {(const float*)d_in[16], (const float*)d_in[19], (const float*)d_in[22]};
  const float* gns[3] = {(const float*)d_in[17], (const float*)d_in[20], (const float*)d_in[23]};
  const float* hw1 = (const float*)d_in[24];
  const float* hb1 = (const float*)d_in[25];
  const float* hw2 = (const float*)d_in[26];
  const float* hb2 = (const float*)d_in[27];
  const float* hw3 = (const float*)d_in[28];
  const float* hb3 = (const float*)d_in[29];
  const float* nw1 = (const float*)d_in[30];
  const float* nb1 = (const float*)d_in[31];
  const float* nw2 = (const float*)d_in[32];
  const float* nb2 = (const float*)d_in[33];

  const int N = in_sizes[0] / D;
  const int E = in_sizes[1] / 2;
  const int* src = eidx;
  const int* dst = eidx + E;

  float* out    = (float*)d_out;
  float* logits = out;
  float* hub    = out + GG * 2;
  float* gf     = out + GG * 2 + N;
  float* X      = out + GG * 2 + N + GG * 256;

  char* wp = (char*)d_ws;
  auto alloc = [&](size_t bytes) { char* p = wp; wp += (bytes + 255) & ~(size_t)255; return p; };
  float*    B1    = (float*)alloc((size_t)N * D * 4);
  float*    B2    = (float*)alloc((size_t)N * D * 4);
  unsigned* B1h   = (unsigned*)alloc((size_t)N * (D / 2) * 4);   // bf16 x2 packed
  int*   col     = (int*)alloc((size_t)E * 4);
  int*   cnt     = (int*)alloc((size_t)N * 4);
  int*   rowp    = (int*)alloc((size_t)(N + 1) * 4);
  int*   cur     = (int*)alloc((size_t)N * 4);
  float* dinv    = (float*)alloc((size_t)N * 4);
  float* es      = (float*)alloc((size_t)N * 4 * 4);
  float* ed      = (float*)alloc((size_t)N * 4 * 4);
  float* aself   = (float*)alloc((size_t)N * 4 * 4);
  float* gsum    = (float*)alloc((size_t)GG * D * 4);
  float* gsq     = (float*)alloc((size_t)GG * D * 4);
  unsigned* gmaxu = (unsigned*)alloc((size_t)GG * D * 4);
  float* mean    = (float*)alloc((size_t)GG * D * 4);
  float* rstd    = (float*)alloc((size_t)GG * D * 4);
  int*   gcnt    = (int*)alloc((size_t)GG * 4);
  int*   gstart  = (int*)alloc((size_t)GG * 4);
  int*   gend    = (int*)alloc((size_t)GG * 4);
  int*   bsum    = (int*)alloc((size_t)256 * 4);
  float* alpha   = B1;   // alias: B1 (fp32 features) is dead once attn_coef_k has read it
  if ((size_t)(wp - (char*)d_ws) > ws_size) return;

  const int nb = (N + 255) / 256;

  // ---- CSR + graph ranges (once) ----
  hipMemsetAsync(cnt, 0, (size_t)N * 4, stream);
  count_edges_k<<<(E + 255) / 256, 256, 0, stream>>>(dst, cnt, E);
  bounds_init_k<<<1, GG, 0, stream>>>(gstart, gend);
  graph_bounds_k<<<nb, 256, 0, stream>>>(batch, gstart, gend, N);
  gcnt_k<<<1, GG, 0, stream>>>(gstart, gend, gcnt);
  scan1_k<<<nb, 256, 0, stream>>>(cnt, rowp, bsum, N);
  scan2_k<<<1, 256, 0, stream>>>(bsum, nb);
  scan3_k<<<nb, 256, 0, stream>>>(rowp, bsum, cur, N, E);
  dinv_k<<<nb, 256, 0, stream>>>(cnt, dinv, N);
  fill_csr_k<<<(E + 255) / 256, 256, 0, stream>>>(src, dst, cur, col, E);

  const int gemmGrid = (N + 63) / 64;
  const int aggGrid  = (N + 3) / 4;

  auto graphnorm = [&](int layer) {
    hipMemsetAsync(gsum, 0, 2 * (size_t)GG * D * 4, stream);
    gn_stats_k<<<GG * SLICES, 256, 0, stream>>>(B2, gstart, gcnt, gsum, gsq);
    gn_finalize_k<<<GG, D, 0, stream>>>(gsum, gsq, gcnt, gns[layer], mean, rstd);
    gn_apply_k<<<(N * 32 + 255) / 256, 256, 0, stream>>>(B2, X, batch, mean, rstd,
                                                         gnw[layer], gnb[layer], gns[layer], N);
  };

  // ---- projection ----
  gemm_k<<<gemmGrid, 256, 0, stream>>>(x_in, Wp, bp, X, nullptr, N);

  // ---- GCN layer ----
  gemm_k<<<gemmGrid, 256, 0, stream>>>(X, Wg, nullptr, B1, B1h, N);
  gcn_gather_k<<<aggGrid, 256, 0, stream>>>(B1h, rowp, col, dinv, bg, B2, N);
  graphnorm(0);

  // ---- GAT layer 1 ----
  gemm_k<<<gemmGrid, 256, 0, stream>>>(X, Wa1, nullptr, B1, B1h, N);
  attn_coef_k<<<(N * 4 + 255) / 256, 256, 0, stream>>>(B1, as1, ad1, es, ed, N);
  alpha_k<<<aggGrid, 256, 0, stream>>>(es, ed, rowp, col, alpha, aself, N);
  gat_gather_k<<<aggGrid, 256, 0, stream>>>(B1h, rowp, col, alpha, aself, ba1, B2, N);
  graphnorm(1);

  // ---- GAT layer 2 ----
  gemm_k<<<gemmGrid, 256, 0, stream>>>(X, Wa2, nullptr, B1, B1h, N);
  attn_coef_k<<<(N * 4 + 255) / 256, 256, 0, stream>>>(B1, as2, ad2, es, ed, N);
  alpha_k<<<aggGrid, 256, 0, stream>>>(es, ed, rowp, col, alpha, aself, N);
  gat_gather_k<<<aggGrid, 256, 0, stream>>>(B1h, rowp, col, alpha, aself, ba2, B2, N);
  graphnorm(2);

  // ---- hub scores ----
  hub_k<<<1024, 256, 0, stream>>>(X, nw1, nb1, nw2, nb2, hub, N);

  // ---- pooling + graph MLP ----
  hipMemsetAsync(gsum, 0, (size_t)GG * D * 4, stream);
  init_maxu_k<<<(GG * D + 255) / 256, 256, 0, stream>>>(gmaxu, GG * D);
  pool_stats_k<<<GG * SLICES, 256, 0, stream>>>(X, gstart, gcnt, gsum, gmaxu);
  pool_fin_k<<<GG, D, 0, stream>>>(gsum, gmaxu, gcnt, gf);
  mlp_k<<<GG, 128, 0, stream>>>(gf, hw1, hb1, hw2, hb2, hw3, hb3, logits);
}

// Round 4
// 464.023 us; speedup vs baseline: 2.2129x; 1.2956x over previous
//
#include <hip/hip_runtime.h>
#include <cstdint>

#define D 128
#define GG 64
#define SLICES 16

typedef short bf16x8 __attribute__((ext_vector_type(8)));
typedef float f32x4 __attribute__((ext_vector_type(4)));

// ---------- bf16 helpers ----------
__device__ inline unsigned packbf2(float a, float b) {
  unsigned ua = __float_as_uint(a), ub = __float_as_uint(b);
  ua = (ua + 0x7FFFu + ((ua >> 16) & 1u)) >> 16;   // RNE
  ub = (ub + 0x7FFFu + ((ub >> 16) & 1u)) >> 16;
  return ua | (ub << 16);
}
__device__ inline unsigned short bf16u(float f) {
  unsigned u = __float_as_uint(f);
  u = (u + 0x7FFFu + ((u >> 16) & 1u)) >> 16;
  return (unsigned short)u;
}
__device__ inline float2 unpackbf2(unsigned u) {
  return make_float2(__uint_as_float(u << 16), __uint_as_float(u & 0xFFFF0000u));
}

// ======================= CSR build =======================
__global__ void count_edges_k(const int* __restrict__ dst, int* __restrict__ cnt, int E) {
  int e = blockIdx.x * blockDim.x + threadIdx.x;
  if (e < E) atomicAdd(&cnt[dst[e]], 1);
}

__global__ void bounds_init_k(int* __restrict__ gstart, int* __restrict__ gend) {
  int g = threadIdx.x;
  gstart[g] = 0;
  gend[g] = 0;
}

__global__ void graph_bounds_k(const int* __restrict__ batch, int* __restrict__ gstart,
                               int* __restrict__ gend, int n) {
  int i = blockIdx.x * blockDim.x + threadIdx.x;
  if (i >= n) return;
  int b = batch[i];
  if (i == 0) {
    gstart[b] = 0;
  } else {
    int pb = batch[i - 1];
    if (pb != b) { gstart[b] = i; gend[pb] = i; }
  }
  if (i == n - 1) gend[b] = n;
}

__global__ void gcnt_k(const int* __restrict__ gstart, const int* __restrict__ gend,
                       int* __restrict__ gcnt) {
  int g = threadIdx.x;
  gcnt[g] = gend[g] - gstart[g];
}

__global__ __launch_bounds__(256) void scan1_k(const int* __restrict__ cnt, int* __restrict__ rp,
                                               int* __restrict__ bsum, int n) {
  __shared__ int sd[256];
  int t = threadIdx.x;
  int i = blockIdx.x * 256 + t;
  int v = (i < n) ? cnt[i] : 0;
  sd[t] = v;
  __syncthreads();
#pragma unroll
  for (int off = 1; off < 256; off <<= 1) {
    int u = (t >= off) ? sd[t - off] : 0;
    __syncthreads();
    sd[t] += u;
    __syncthreads();
  }
  if (i < n) rp[i] = sd[t] - v;
  if (t == 255) bsum[blockIdx.x] = sd[255];
}

__global__ __launch_bounds__(256) void scan2_k(int* __restrict__ bsum, int nb) {
  __shared__ int sd[256];
  int t = threadIdx.x;
  int v = (t < nb) ? bsum[t] : 0;
  sd[t] = v;
  __syncthreads();
#pragma unroll
  for (int off = 1; off < 256; off <<= 1) {
    int u = (t >= off) ? sd[t - off] : 0;
    __syncthreads();
    sd[t] += u;
    __syncthreads();
  }
  if (t < nb) bsum[t] = sd[t] - v;
}

__global__ __launch_bounds__(256) void scan3_k(int* __restrict__ rp, const int* __restrict__ bsum,
                                               int* __restrict__ cur, int n, int E) {
  int i = blockIdx.x * 256 + threadIdx.x;
  if (i < n) {
    int r = rp[i] + bsum[blockIdx.x];
    rp[i] = r;
    cur[i] = r;
  }
  if (i == 0) rp[n] = E;
}

__global__ void fill_csr_k(const int* __restrict__ src, const int* __restrict__ dst,
                           int* __restrict__ cur, int* __restrict__ col, int E) {
  int e = blockIdx.x * blockDim.x + threadIdx.x;
  if (e >= E) return;
  int p = atomicAdd(&cur[dst[e]], 1);
  col[p] = src[e];
}

__global__ void dinv_k(const int* __restrict__ cnt, float* __restrict__ dinv, int n) {
  int i = blockIdx.x * blockDim.x + threadIdx.x;
  if (i < n) dinv[i] = rsqrtf((float)cnt[i] + 1.0f);
}

// ======================= bf16 cast =======================
__global__ void cast_bf16_k(const float* __restrict__ in, unsigned short* __restrict__ outp, int n4) {
  int i = blockIdx.x * blockDim.x + threadIdx.x;
  if (i >= n4) return;
  float4 v = ((const float4*)in)[i];
  ushort4 o;
  o.x = bf16u(v.x); o.y = bf16u(v.y); o.z = bf16u(v.z); o.w = bf16u(v.w);
  ((ushort4*)outp)[i] = o;
}

// ======================= Weight pack into MFMA B-fragment order =======================
// Bp[((c*4+kc)*64+lane)*8 + j] = bf16(B[kc*32+(lane>>4)*8+j][c*16+(lane&15)])
__global__ void packB_k(const float* __restrict__ B, unsigned short* __restrict__ Bp, int ldb, int ct) {
  int idx = blockIdx.x * 256 + threadIdx.x;
  if (idx >= ct * 256) return;
  int lane = idx & 63;
  int kc = (idx >> 6) & 3;
  int c = idx >> 8;
  int kb = kc * 32 + (lane >> 4) * 8;
  int colq = c * 16 + (lane & 15);
  unsigned short o[8];
#pragma unroll
  for (int j = 0; j < 8; ++j) o[j] = bf16u(B[(size_t)(kb + j) * ldb + colq]);
  uint4 p;
  p.x = (unsigned)o[0] | ((unsigned)o[1] << 16);
  p.y = (unsigned)o[2] | ((unsigned)o[3] << 16);
  p.z = (unsigned)o[4] | ((unsigned)o[5] << 16);
  p.w = (unsigned)o[6] | ((unsigned)o[7] << 16);
  *(uint4*)&Bp[(size_t)idx * 8] = p;
}

// ======================= MFMA GEMM: [M,128]x[128,128] =======================
__global__ __launch_bounds__(256) void gemm_mfma_k(const unsigned short* __restrict__ Ab,
                                                   const unsigned short* __restrict__ Bp,
                                                   const float* __restrict__ bias,
                                                   float* __restrict__ Cf,
                                                   unsigned short* __restrict__ Cb, int M) {
  __shared__ unsigned short Bs[16384];   // 32 KB: 8 coltiles x 4 kc x 64 lanes x 8 bf16
  int t = threadIdx.x;
  for (int i = t; i < 2048; i += 256) ((uint4*)Bs)[i] = ((const uint4*)Bp)[i];
  __syncthreads();
  int w = t >> 6, lane = t & 63;
  int row0 = blockIdx.x * 64 + w * 16;
  int arow = row0 + (lane & 15);
  f32x4 acc[8];
#pragma unroll
  for (int c = 0; c < 8; ++c) acc[c] = {0.f, 0.f, 0.f, 0.f};
#pragma unroll
  for (int kc = 0; kc < 4; ++kc) {
    bf16x8 a = {0, 0, 0, 0, 0, 0, 0, 0};
    if (arow < M) a = *(const bf16x8*)&Ab[(size_t)arow * 128 + kc * 32 + (lane >> 4) * 8];
#pragma unroll
    for (int c = 0; c < 8; ++c) {
      bf16x8 b = *(const bf16x8*)&Bs[((c * 4 + kc) * 64 + lane) * 8];
      acc[c] = __builtin_amdgcn_mfma_f32_16x16x32_bf16(a, b, acc[c], 0, 0, 0);
    }
  }
  int rbase = row0 + (lane >> 4) * 4;
#pragma unroll
  for (int c = 0; c < 8; ++c) {
    int colq = c * 16 + (lane & 15);
    float bb = bias ? bias[colq] : 0.f;
#pragma unroll
    for (int r = 0; r < 4; ++r) {
      int row = rbase + r;
      if (row < M) {
        float v = acc[c][r] + bb;
        if (Cf) Cf[(size_t)row * 128 + colq] = v;
        if (Cb) Cb[(size_t)row * 128 + colq] = bf16u(v);
      }
    }
  }
}

// ======================= GCN aggregation (bf16 gathers, 4-way unroll) =======================
__global__ __launch_bounds__(256) void gcn_gather_k(const unsigned* __restrict__ xwb,
                                                    const int* __restrict__ rp, const int* __restrict__ col,
                                                    const float* __restrict__ dinv, const float* __restrict__ bias,
                                                    float* __restrict__ out, int n) {
  int i = blockIdx.x * 4 + (threadIdx.x >> 6);
  if (i >= n) return;
  int lane = threadIdx.x & 63;
  int e0 = __builtin_amdgcn_readfirstlane(rp[i]);
  int e1 = __builtin_amdgcn_readfirstlane(rp[i + 1]);
  float di = dinv[i];
  float2 sv = unpackbf2(xwb[(size_t)i * 64 + lane]);
  float ax0 = sv.x * di * di, ay0 = sv.y * di * di;
  float ax1 = 0.f, ay1 = 0.f, ax2 = 0.f, ay2 = 0.f, ax3 = 0.f, ay3 = 0.f;
  int e = e0;
  for (; e + 3 < e1; e += 4) {
    int s0 = __builtin_amdgcn_readfirstlane(col[e]);
    int s1 = __builtin_amdgcn_readfirstlane(col[e + 1]);
    int s2 = __builtin_amdgcn_readfirstlane(col[e + 2]);
    int s3 = __builtin_amdgcn_readfirstlane(col[e + 3]);
    float w0 = dinv[s0] * di, w1 = dinv[s1] * di, w2 = dinv[s2] * di, w3 = dinv[s3] * di;
    float2 v0 = unpackbf2(xwb[(size_t)s0 * 64 + lane]);
    float2 v1 = unpackbf2(xwb[(size_t)s1 * 64 + lane]);
    float2 v2 = unpackbf2(xwb[(size_t)s2 * 64 + lane]);
    float2 v3 = unpackbf2(xwb[(size_t)s3 * 64 + lane]);
    ax0 += v0.x * w0; ay0 += v0.y * w0;
    ax1 += v1.x * w1; ay1 += v1.y * w1;
    ax2 += v2.x * w2; ay2 += v2.y * w2;
    ax3 += v3.x * w3; ay3 += v3.y * w3;
  }
  for (; e < e1; ++e) {
    int s0 = __builtin_amdgcn_readfirstlane(col[e]);
    float w0 = dinv[s0] * di;
    float2 v0 = unpackbf2(xwb[(size_t)s0 * 64 + lane]);
    ax0 += v0.x * w0; ay0 += v0.y * w0;
  }
  float2 bb = ((const float2*)bias)[lane];
  ((float2*)out)[(size_t)i * 64 + lane] =
      make_float2(ax0 + ax1 + ax2 + ax3 + bb.x, ay0 + ay1 + ay2 + ay3 + bb.y);
}

// ======================= GAT attention coefficients (bf16 input) =======================
__global__ void attn_coef_k(const unsigned short* __restrict__ hb, const float* __restrict__ a_s,
                            const float* __restrict__ a_d, float* __restrict__ es,
                            float* __restrict__ ed, int n) {
  int idx = blockIdx.x * blockDim.x + threadIdx.x;
  if (idx >= n * 4) return;
  int node = idx >> 2, hh = idx & 3;
  const uint4* hr = (const uint4*)(hb + (size_t)node * 128 + hh * 32);
  const float4* av = (const float4*)(a_s + hh * 32);
  const float4* dv = (const float4*)(a_d + hh * 32);
  float s = 0.f, d2 = 0.f;
#pragma unroll
  for (int q = 0; q < 4; ++q) {
    uint4 u = hr[q];
    float2 p0 = unpackbf2(u.x), p1 = unpackbf2(u.y), p2 = unpackbf2(u.z), p3 = unpackbf2(u.w);
    float4 a0 = av[q * 2], a1 = av[q * 2 + 1];
    float4 d0 = dv[q * 2], d1 = dv[q * 2 + 1];
    s  += p0.x * a0.x + p0.y * a0.y + p1.x * a0.z + p1.y * a0.w
        + p2.x * a1.x + p2.y * a1.y + p3.x * a1.z + p3.y * a1.w;
    d2 += p0.x * d0.x + p0.y * d0.y + p1.x * d0.z + p1.y * d0.w
        + p2.x * d1.x + p2.y * d1.y + p3.x * d1.z + p3.y * d1.w;
  }
  es[idx] = s;
  ed[idx] = d2;
}

// ======================= GAT alpha precompute =======================
__global__ __launch_bounds__(256) void alpha_k(const float* __restrict__ es, const float* __restrict__ ed,
                                               const int* __restrict__ rp, const int* __restrict__ col,
                                               float* __restrict__ alpha, float* __restrict__ aself, int n) {
  int i = blockIdx.x * 4 + (threadIdx.x >> 6);
  if (i >= n) return;
  int lane = threadIdx.x & 63;
  int hh = lane >> 4, slot = lane & 15;
  int e0 = __builtin_amdgcn_readfirstlane(rp[i]);
  int e1 = __builtin_amdgcn_readfirstlane(rp[i + 1]);
  float edi = ed[i * 4 + hh];
  float esf = es[i * 4 + hh] + edi;
  esf = esf >= 0.f ? esf : 0.2f * esf;
  float m = esf;
  for (int e = e0 + slot; e < e1; e += 16) {
    int sj = col[e];
    float ev = es[sj * 4 + hh] + edi;
    ev = ev >= 0.f ? ev : 0.2f * ev;
    alpha[(size_t)e * 4 + hh] = ev;
    m = fmaxf(m, ev);
  }
#pragma unroll
  for (int off = 1; off < 16; off <<= 1) m = fmaxf(m, __shfl_xor(m, off, 64));
  float s = (slot == 0) ? __expf(esf - m) : 0.f;
  for (int e = e0 + slot; e < e1; e += 16) {
    float w = __expf(alpha[(size_t)e * 4 + hh] - m);
    alpha[(size_t)e * 4 + hh] = w;
    s += w;
  }
#pragma unroll
  for (int off = 1; off < 16; off <<= 1) s += __shfl_xor(s, off, 64);
  float winv = 1.0f / (s + 1e-16f);
  for (int e = e0 + slot; e < e1; e += 16) {
    alpha[(size_t)e * 4 + hh] *= winv;
  }
  if (slot == 0) aself[i * 4 + hh] = __expf(esf - m) * winv;
}

// ======================= GAT gather (bf16, precomputed alpha, 4-way) =======================
__global__ __launch_bounds__(256) void gat_gather_k(const unsigned* __restrict__ hfb,
                                                    const int* __restrict__ rp, const int* __restrict__ col,
                                                    const float* __restrict__ alpha, const float* __restrict__ aself,
                                                    const float* __restrict__ bias, float* __restrict__ out, int n) {
  int i = blockIdx.x * 4 + (threadIdx.x >> 6);
  if (i >= n) return;
  int lane = threadIdx.x & 63;
  int hh = lane >> 4;
  int e0 = __builtin_amdgcn_readfirstlane(rp[i]);
  int e1 = __builtin_amdgcn_readfirstlane(rp[i + 1]);
  float2 sv = unpackbf2(hfb[(size_t)i * 64 + lane]);
  float a0 = aself[i * 4 + hh];
  float ax0 = sv.x * a0, ay0 = sv.y * a0;
  float ax1 = 0.f, ay1 = 0.f, ax2 = 0.f, ay2 = 0.f, ax3 = 0.f, ay3 = 0.f;
  int e = e0;
  for (; e + 3 < e1; e += 4) {
    int s0 = __builtin_amdgcn_readfirstlane(col[e]);
    int s1 = __builtin_amdgcn_readfirstlane(col[e + 1]);
    int s2 = __builtin_amdgcn_readfirstlane(col[e + 2]);
    int s3 = __builtin_amdgcn_readfirstlane(col[e + 3]);
    float aa0 = alpha[(size_t)e * 4 + hh];
    float aa1 = alpha[(size_t)(e + 1) * 4 + hh];
    float aa2 = alpha[(size_t)(e + 2) * 4 + hh];
    float aa3 = alpha[(size_t)(e + 3) * 4 + hh];
    float2 v0 = unpackbf2(hfb[(size_t)s0 * 64 + lane]);
    float2 v1 = unpackbf2(hfb[(size_t)s1 * 64 + lane]);
    float2 v2 = unpackbf2(hfb[(size_t)s2 * 64 + lane]);
    float2 v3 = unpackbf2(hfb[(size_t)s3 * 64 + lane]);
    ax0 += v0.x * aa0; ay0 += v0.y * aa0;
    ax1 += v1.x * aa1; ay1 += v1.y * aa1;
    ax2 += v2.x * aa2; ay2 += v2.y * aa2;
    ax3 += v3.x * aa3; ay3 += v3.y * aa3;
  }
  for (; e < e1; ++e) {
    int s0 = __builtin_amdgcn_readfirstlane(col[e]);
    float aa0 = alpha[(size_t)e * 4 + hh];
    float2 v0 = unpackbf2(hfb[(size_t)s0 * 64 + lane]);
    ax0 += v0.x * aa0; ay0 += v0.y * aa0;
  }
  float2 bb = ((const float2*)bias)[lane];
  ((float2*)out)[(size_t)i * 64 + lane] =
      make_float2(ax0 + ax1 + ax2 + ax3 + bb.x, ay0 + ay1 + ay2 + ay3 + bb.y);
}

// ======================= GraphNorm =======================
__global__ __launch_bounds__(256) void gn_stats_k(const float* __restrict__ h, const int* __restrict__ gstart,
                                                  const int* __restrict__ gcnt, float* __restrict__ gsum,
                                                  float* __restrict__ gsq) {
  int g = blockIdx.x / SLICES, sl = blockIdx.x % SLICES;
  int st = gstart[g], cn = gcnt[g];
  int d = threadIdx.x & 127, half = threadIdx.x >> 7;
  float s = 0.f, ss = 0.f;
  for (int r = sl * 2 + half; r < cn; r += 2 * SLICES) {
    float v = h[(size_t)(st + r) * D + d];
    s += v; ss += v * v;
  }
  __shared__ float l1[128], l2[128];
  if (half) { l1[d] = s; l2[d] = ss; }
  __syncthreads();
  if (!half) {
    atomicAdd(&gsum[g * D + d], s + l1[d]);
    atomicAdd(&gsq[g * D + d], ss + l2[d]);
  }
}

__global__ void gn_finalize_k(const float* __restrict__ gsum, const float* __restrict__ gsq,
                              const int* __restrict__ gcnt, const float* __restrict__ ms,
                              float* __restrict__ mean, float* __restrict__ rstd) {
  int g = blockIdx.x, d = threadIdx.x;
  float cnt = fmaxf((float)gcnt[g], 1.0f);
  float mu = gsum[g * D + d] / cnt;
  float m2 = gsq[g * D + d] / cnt;
  float s = ms[d];
  float var = m2 - (2.0f * s - s * s) * mu * mu;
  mean[g * D + d] = mu;
  rstd[g * D + d] = rsqrtf(fmaxf(var, 0.0f) + 1e-5f);
}

__global__ void gn_apply_k(const float* __restrict__ h, float* __restrict__ x,
                           unsigned short* __restrict__ xb,
                           const int* __restrict__ batch, const float* __restrict__ mean,
                           const float* __restrict__ rstd, const float* __restrict__ w,
                           const float* __restrict__ b, const float* __restrict__ ms, int n) {
  int idx = blockIdx.x * blockDim.x + threadIdx.x;
  if (idx >= n * 32) return;
  int node = idx >> 5, q = idx & 31;
  int g = batch[node];
  int d0 = q * 4;
  float4 hv = ((const float4*)h)[idx];
  float4 xv = ((const float4*)x)[idx];
  float ha[4] = {hv.x, hv.y, hv.z, hv.w};
  float xa[4] = {xv.x, xv.y, xv.z, xv.w};
  float ra[4];
#pragma unroll
  for (int j = 0; j < 4; ++j) {
    int d = d0 + j;
    float sub = ha[j] - ms[d] * mean[g * D + d];
    float v = w[d] * sub * rstd[g * D + d] + b[d];
    ra[j] = fmaxf(v, 0.f) + xa[j];
  }
  ((float4*)x)[idx] = make_float4(ra[0], ra[1], ra[2], ra[3]);
  ushort4 o;
  o.x = bf16u(ra[0]); o.y = bf16u(ra[1]); o.z = bf16u(ra[2]); o.w = bf16u(ra[3]);
  ((ushort4*)xb)[idx] = o;
}

// ======================= Hub scores (MFMA) =======================
__global__ __launch_bounds__(256) void hub_mfma_k(const unsigned short* __restrict__ Xb,
                                                  const unsigned short* __restrict__ W1p,
                                                  const float* __restrict__ nb1, const float* __restrict__ nw2,
                                                  const float* __restrict__ nb2, float* __restrict__ out, int n) {
  __shared__ unsigned short Bs[8192];   // 16 KB: 4 coltiles x 4 kc x 64 x 8
  int t = threadIdx.x;
  for (int i = t; i < 1024; i += 256) ((uint4*)Bs)[i] = ((const uint4*)W1p)[i];
  __syncthreads();
  int w = t >> 6, lane = t & 63;
  int row0 = blockIdx.x * 64 + w * 16;
  int arow = row0 + (lane & 15);
  f32x4 acc[4];
#pragma unroll
  for (int c = 0; c < 4; ++c) acc[c] = {0.f, 0.f, 0.f, 0.f};
#pragma unroll
  for (int kc = 0; kc < 4; ++kc) {
    bf16x8 a = {0, 0, 0, 0, 0, 0, 0, 0};
    if (arow < n) a = *(const bf16x8*)&Xb[(size_t)arow * 128 + kc * 32 + (lane >> 4) * 8];
#pragma unroll
    for (int c = 0; c < 4; ++c) {
      bf16x8 b = *(const bf16x8*)&Bs[((c * 4 + kc) * 64 + lane) * 8];
      acc[c] = __builtin_amdgcn_mfma_f32_16x16x32_bf16(a, b, acc[c], 0, 0, 0);
    }
  }
  float b2 = nb2[0];
  float s[4] = {0.f, 0.f, 0.f, 0.f};
#pragma unroll
  for (int c = 0; c < 4; ++c) {
    int colq = c * 16 + (lane & 15);
    float b1 = nb1[colq];
    float w2 = nw2[colq];
#pragma unroll
    for (int r = 0; r < 4; ++r) s[r] += fmaxf(acc[c][r] + b1, 0.f) * w2;
  }
#pragma unroll
  for (int off = 1; off < 16; off <<= 1) {
#pragma unroll
    for (int r = 0; r < 4; ++r) s[r] += __shfl_xor(s[r], off, 64);
  }
  if ((lane & 15) == 0) {
    int rbase = row0 + (lane >> 4) * 4;
#pragma unroll
    for (int r = 0; r < 4; ++r) {
      int row = rbase + r;
      if (row < n) out[row] = 1.0f / (1.0f + __expf(-(s[r] + b2)));
    }
  }
}

// ======================= Pooling =======================
__global__ void init_maxu_k(unsigned* __restrict__ p, int n) {
  int i = blockIdx.x * blockDim.x + threadIdx.x;
  if (i < n) p[i] = 0x007FFFFFu;
}

__global__ __launch_bounds__(256) void pool_stats_k(const float* __restrict__ x, const int* __restrict__ gstart,
                                                    const int* __restrict__ gcnt, float* __restrict__ gsum,
                                                    unsigned* __restrict__ gmaxu) {
  int g = blockIdx.x / SLICES, sl = blockIdx.x % SLICES;
  int st = gstart[g], cn = gcnt[g];
  int d = threadIdx.x & 127, half = threadIdx.x >> 7;
  float s = 0.f, mx = __uint_as_float(0xFF800000u);
  for (int r = sl * 2 + half; r < cn; r += 2 * SLICES) {
    float v = x[(size_t)(st + r) * D + d];
    s += v; mx = fmaxf(mx, v);
  }
  __shared__ float l1[128], l2[128];
  if (half) { l1[d] = s; l2[d] = mx; }
  __syncthreads();
  if (!half) {
    s += l1[d];
    mx = fmaxf(mx, l2[d]);
    atomicAdd(&gsum[g * D + d], s);
    unsigned u = __float_as_uint(mx);
    u = (u & 0x80000000u) ? ~u : (u | 0x80000000u);
    atomicMax(&gmaxu[g * D + d], u);
  }
}

__global__ void pool_fin_k(const float* __restrict__ gsum, const unsigned* __restrict__ gmaxu,
                           const int* __restrict__ gcnt, float* __restrict__ gf) {
  int g = blockIdx.x, d = threadIdx.x;
  float cnt = fmaxf((float)gcnt[g], 1.0f);
  gf[g * 256 + d] = gsum[g * D + d] / cnt;
  unsigned u = gmaxu[g * D + d];
  unsigned bits = (u & 0x80000000u) ? (u ^ 0x80000000u) : ~u;
  gf[g * 256 + 128 + d] = __uint_as_float(bits);
}

// ======================= Graph MLP =======================
__global__ __launch_bounds__(128) void mlp_k(const float* __restrict__ gf, const float* __restrict__ hw1,
                                             const float* __restrict__ hb1, const float* __restrict__ hw2,
                                             const float* __restrict__ hb2, const float* __restrict__ hw3,
                                             const float* __restrict__ hb3, float* __restrict__ logits) {
  __shared__ float sg[256], z1[128], z2[64];
  int g = blockIdx.x, t = threadIdx.x;
  sg[t] = gf[g * 256 + t];
  sg[t + 128] = gf[g * 256 + 128 + t];
  __syncthreads();
  float a = hb1[t];
  for (int k = 0; k < 256; ++k) a += sg[k] * hw1[k * 128 + t];
  z1[t] = fmaxf(a, 0.f);
  __syncthreads();
  if (t < 64) {
    float a2 = hb2[t];
    for (int k = 0; k < 128; ++k) a2 += z1[k] * hw2[k * 64 + t];
    z2[t] = fmaxf(a2, 0.f);
  }
  __syncthreads();
  if (t < 2) {
    float a3 = hb3[t];
    for (int k = 0; k < 64; ++k) a3 += z2[k] * hw3[k * 2 + t];
    logits[g * 2 + t] = a3;
  }
}

// ======================= Host =======================
extern "C" void kernel_launch(void* const* d_in, const int* in_sizes, int n_in,
                              void* d_out, int out_size, void* d_ws, size_t ws_size,
                              hipStream_t stream) {
  const float* x_in  = (const float*)d_in[0];
  const int*   eidx  = (const int*)d_in[1];
  const int*   batch = (const int*)d_in[2];
  const float* Wp  = (const float*)d_in[3];
  const float* bp  = (const float*)d_in[4];
  const float* Wg  = (const float*)d_in[5];
  const float* bg  = (const float*)d_in[6];
  const float* Wa1 = (const float*)d_in[7];
  const float* as1 = (const float*)d_in[8];
  const float* ad1 = (const float*)d_in[9];
  const float* ba1 = (const float*)d_in[10];
  const float* Wa2 = (const float*)d_in[11];
  const float* as2 = (const float*)d_in[12];
  const float* ad2 = (const float*)d_in[13];
  const float* ba2 = (const float*)d_in[14];
  const float* gnw[3] = {(const float*)d_in[15], (const float*)d_in[18], (const float*)d_in[21]};
  const float* gnb[3] = {(const float*)d_in[16], (const float*)d_in[19], (const float*)d_in[22]};
  const float* gns[3] = {(const float*)d_in[17], (const float*)d_in[20], (const float*)d_in[23]};
  const float* hw1 = (const float*)d_in[24];
  const float* hb1 = (const float*)d_in[25];
  const float* hw2 = (const float*)d_in[26];
  const float* hb2 = (const float*)d_in[27];
  const float* hw3 = (const float*)d_in[28];
  const float* hb3 = (const float*)d_in[29];
  const float* nw1 = (const float*)d_in[30];
  const float* nb1 = (const float*)d_in[31];
  const float* nw2 = (const float*)d_in[32];
  const float* nb2 = (const float*)d_in[33];

  const int N = in_sizes[0] / D;
  const int E = in_sizes[1] / 2;
  const int* src = eidx;
  const int* dst = eidx + E;

  float* out    = (float*)d_out;
  float* logits = out;
  float* hub    = out + GG * 2;
  float* gf     = out + GG * 2 + N;
  float* X      = out + GG * 2 + N + GG * 256;

  char* wp = (char*)d_ws;
  auto alloc = [&](size_t bytes) { char* p = wp; wp += (bytes + 255) & ~(size_t)255; return p; };
  float*    B1    = (float*)alloc((size_t)N * D * 4);       // scratch: alpha
  float*    B2    = (float*)alloc((size_t)N * D * 4);       // agg out; also aliases x_in bf16 early
  unsigned* B1h   = (unsigned*)alloc((size_t)N * (D / 2) * 4);
  unsigned short* Xb = (unsigned short*)alloc((size_t)N * D * 2);
  int*   col     = (int*)alloc((size_t)E * 4);
  int*   cnt     = (int*)alloc((size_t)N * 4);
  int*   rowp    = (int*)alloc((size_t)(N + 1) * 4);
  int*   cur     = (int*)alloc((size_t)N * 4);
  float* dinv    = (float*)alloc((size_t)N * 4);
  float* es      = (float*)alloc((size_t)N * 4 * 4);
  float* ed      = (float*)alloc((size_t)N * 4 * 4);
  float* aself   = (float*)alloc((size_t)N * 4 * 4);
  float* gsum    = (float*)alloc((size_t)GG * D * 4);
  float* gsq     = (float*)alloc((size_t)GG * D * 4);
  unsigned* gmaxu = (unsigned*)alloc((size_t)GG * D * 4);
  float* mean    = (float*)alloc((size_t)GG * D * 4);
  float* rstd    = (float*)alloc((size_t)GG * D * 4);
  int*   gcnt    = (int*)alloc((size_t)GG * 4);
  int*   gstart  = (int*)alloc((size_t)GG * 4);
  int*   gend    = (int*)alloc((size_t)GG * 4);
  int*   bsum    = (int*)alloc((size_t)256 * 4);
  unsigned short* Wpp  = (unsigned short*)alloc(16384 * 2);
  unsigned short* Wgp  = (unsigned short*)alloc(16384 * 2);
  unsigned short* Wa1p = (unsigned short*)alloc(16384 * 2);
  unsigned short* Wa2p = (unsigned short*)alloc(16384 * 2);
  unsigned short* W1p  = (unsigned short*)alloc(8192 * 2);
  float* alpha = B1;                          // alias (B1 is pure scratch now)
  unsigned short* xinb = (unsigned short*)B2; // alias: consumed before B2 first written
  if ((size_t)(wp - (char*)d_ws) > ws_size) return;

  const int nb = (N + 255) / 256;

  // ---- CSR + graph ranges ----
  hipMemsetAsync(cnt, 0, (size_t)N * 4, stream);
  count_edges_k<<<(E + 255) / 256, 256, 0, stream>>>(dst, cnt, E);
  bounds_init_k<<<1, GG, 0, stream>>>(gstart, gend);
  graph_bounds_k<<<nb, 256, 0, stream>>>(batch, gstart, gend, N);
  gcnt_k<<<1, GG, 0, stream>>>(gstart, gend, gcnt);
  scan1_k<<<nb, 256, 0, stream>>>(cnt, rowp, bsum, N);
  scan2_k<<<1, 256, 0, stream>>>(bsum, nb);
  scan3_k<<<nb, 256, 0, stream>>>(rowp, bsum, cur, N, E);
  dinv_k<<<nb, 256, 0, stream>>>(cnt, dinv, N);
  fill_csr_k<<<(E + 255) / 256, 256, 0, stream>>>(src, dst, cur, col, E);

  // ---- weight packs + input cast ----
  packB_k<<<8, 256, 0, stream>>>(Wp, Wpp, 128, 8);
  packB_k<<<8, 256, 0, stream>>>(Wg, Wgp, 128, 8);
  packB_k<<<8, 256, 0, stream>>>(Wa1, Wa1p, 128, 8);
  packB_k<<<8, 256, 0, stream>>>(Wa2, Wa2p, 128, 8);
  packB_k<<<4, 256, 0, stream>>>(nw1, W1p, 64, 4);
  cast_bf16_k<<<(N * 32 + 255) / 256, 256, 0, stream>>>(x_in, xinb, N * 32);

  const int gemmGrid = (N + 63) / 64;
  const int aggGrid  = (N + 3) / 4;

  auto graphnorm = [&](int layer) {
    hipMemsetAsync(gsum, 0, 2 * (size_t)GG * D * 4, stream);
    gn_stats_k<<<GG * SLICES, 256, 0, stream>>>(B2, gstart, gcnt, gsum, gsq);
    gn_finalize_k<<<GG, D, 0, stream>>>(gsum, gsq, gcnt, gns[layer], mean, rstd);
    gn_apply_k<<<(N * 32 + 255) / 256, 256, 0, stream>>>(B2, X, Xb, batch, mean, rstd,
                                                         gnw[layer], gnb[layer], gns[layer], N);
  };

  // ---- projection ----
  gemm_mfma_k<<<gemmGrid, 256, 0, stream>>>(xinb, Wpp, bp, X, Xb, N);

  // ---- GCN layer ----
  gemm_mfma_k<<<gemmGrid, 256, 0, stream>>>(Xb, Wgp, nullptr, nullptr, (unsigned short*)B1h, N);
  gcn_gather_k<<<aggGrid, 256, 0, stream>>>(B1h, rowp, col, dinv, bg, B2, N);
  graphnorm(0);

  // ---- GAT layer 1 ----
  gemm_mfma_k<<<gemmGrid, 256, 0, stream>>>(Xb, Wa1p, nullptr, nullptr, (unsigned short*)B1h, N);
  attn_coef_k<<<(N * 4 + 255) / 256, 256, 0, stream>>>((const unsigned short*)B1h, as1, ad1, es, ed, N);
  alpha_k<<<aggGrid, 256, 0, stream>>>(es, ed, rowp, col, alpha, aself, N);
  gat_gather_k<<<aggGrid, 256, 0, stream>>>(B1h, rowp, col, alpha, aself, ba1, B2, N);
  graphnorm(1);

  // ---- GAT layer 2 ----
  gemm_mfma_k<<<gemmGrid, 256, 0, stream>>>(Xb, Wa2p, nullptr, nullptr, (unsigned short*)B1h, N);
  attn_coef_k<<<(N * 4 + 255) / 256, 256, 0, stream>>>((const unsigned short*)B1h, as2, ad2, es, ed, N);
  alpha_k<<<aggGrid, 256, 0, stream>>>(es, ed, rowp, col, alpha, aself, N);
  gat_gather_k<<<aggGrid, 256, 0, stream>>>(B1h, rowp, col, alpha, aself, ba2, B2, N);
  graphnorm(2);

  // ---- hub scores (MFMA) ----
  hub_mfma_k<<<gemmGrid, 256, 0, stream>>>(Xb, W1p, nb1, nw2, nb2, hub, N);

  // ---- pooling + graph MLP ----
  hipMemsetAsync(gsum, 0, (size_t)GG * D * 4, stream);
  init_maxu_k<<<(GG * D + 255) / 256, 256, 0, stream>>>(gmaxu, GG * D);
  pool_stats_k<<<GG * SLICES, 256, 0, stream>>>(X, gstart, gcnt, gsum, gmaxu);
  pool_fin_k<<<GG, D, 0, stream>>>(gsum, gmaxu, gcnt, gf);
  mlp_k<<<GG, 128, 0, stream>>>(gf, hw1, hb1, hw2, hb2, hw3, hb3, logits);
}